// Round 7
// baseline (5083.106 us; speedup 1.0000x reference)
//
#include <hip/hip_runtime.h>
#include <hip/hip_bf16.h>

#define DEV __device__ __forceinline__

constexpr int B = 64, S = 128, T = 32, H = 1024, V = 32000;
constexpr int H4 = 4096;          // 4*H
constexpr int KX = 3072;          // [emb | ctx | h]
constexpr int NBL = V / 64;       // 500 logits N-tiles
constexpr int BH = B * H;

using f32x4   = __attribute__((ext_vector_type(4))) float;
using short8v = __attribute__((ext_vector_type(8))) short;

DEV unsigned short f2bf(float x) {
  union { __hip_bfloat16 b; unsigned short u; } v;
  v.b = __float2bfloat16(x);
  return v.u;
}
DEV float fast_sig(float x) { return 1.0f / (1.0f + __expf(-x)); }
DEV float fast_tanh(float x) {
  float e = __expf(2.0f * x);
  return 1.0f - 2.0f / (e + 1.0f);
}
DEV float bfl(unsigned u) { return __uint_as_float(u << 16); }
DEV float bfh(unsigned u) { return __uint_as_float(u & 0xffff0000u); }

DEV void gload16(const void* g, void* l) {
  __builtin_amdgcn_global_load_lds(
      (const __attribute__((address_space(1))) void*)g,
      (__attribute__((address_space(3))) void*)l, 16, 0, 0);
}

// ---------------- LDS ----------------
struct GemmSm {
  unsigned short As[3][4096];
  unsigned short Bs[3][4096];
  float Pm[4][64];
  float Pl[4][64];
};
struct AttnSm { float hv[H]; float qw[H]; float sc[S]; float al[S]; };
struct LogZSm { float rm[256]; float rl[256]; };
union K1U { AttnSm a; LogZSm z; };

// ============ pipelined bf16 GEMM body (M=64, Ntile=64, BK=64) ============
// verified fragment layout: lane l's 16B at l*16 -> row=mb*16+(l&15),
// k=ks*32+(l>>4)*8..+7 ; 3 LDS buffers, 2-deep prefetch, counted vmcnt.
template<bool PARTIALS>
DEV void gemm_body2(GemmSm& sm,
                    const unsigned short* __restrict__ A, int lda,
                    const unsigned short* __restrict__ W, int ldw,
                    int K, int n0,
                    float* __restrict__ C, size_t ldc,
                    const float* __restrict__ bias,
                    float* __restrict__ pm, float* __restrict__ pl, int pmb)
{
  const int tid = threadIdx.x;
  const int l   = tid & 63;
  const int w   = tid >> 6;

  f32x4 acc0 = {0,0,0,0}, acc1 = {0,0,0,0}, acc2 = {0,0,0,0}, acc3 = {0,0,0,0};

  const int rA = l & 15;
  const int kq = (l >> 4) << 3;

  auto stage = [&](int k0, int buf) {
    #pragma unroll
    for (int i = 0; i < 4; ++i) {
      const int c    = (w << 2) | i;
      const int side = c >> 3;
      const int ks   = (c >> 2) & 1;
      const int mb   = c & 3;
      const int kk   = k0 + ks * 32 + kq;
      const int row  = mb * 16 + rA;
      const unsigned short* src = side
        ? W + (size_t)(n0 + row) * ldw + kk
        : A + (size_t)row * lda + kk;
      unsigned short* dst = (side ? sm.Bs[buf] : sm.As[buf]) + ks * 2048 + mb * 512;
      gload16(src, dst);
    }
  };

  const int nk = K >> 6;
  stage(0, 0);
  if (nk > 1) stage(64, 1);
  for (int kt = 0; kt < nk; ++kt) {
    const int buf = kt % 3;
    if (kt + 2 < nk) {
      stage((kt + 2) << 6, (kt + 2) % 3);
      asm volatile("s_waitcnt vmcnt(8)" ::: "memory");
    } else if (kt + 1 < nk) {
      asm volatile("s_waitcnt vmcnt(4)" ::: "memory");
    } else {
      asm volatile("s_waitcnt vmcnt(0)" ::: "memory");
    }
    __builtin_amdgcn_s_barrier();
    asm volatile("" ::: "memory");
    const unsigned short* __restrict__ asb = sm.As[buf];
    const unsigned short* __restrict__ bsb = sm.Bs[buf];
    #pragma unroll
    for (int ks = 0; ks < 2; ++ks) {
      short8v bf = *(const short8v*)&bsb[ks * 2048 + (w << 9) + (l << 3)];
      acc0 = __builtin_amdgcn_mfma_f32_16x16x32_bf16(*(const short8v*)&asb[ks * 2048 + 0 * 512 + (l << 3)], bf, acc0, 0, 0, 0);
      acc1 = __builtin_amdgcn_mfma_f32_16x16x32_bf16(*(const short8v*)&asb[ks * 2048 + 1 * 512 + (l << 3)], bf, acc1, 0, 0, 0);
      acc2 = __builtin_amdgcn_mfma_f32_16x16x32_bf16(*(const short8v*)&asb[ks * 2048 + 2 * 512 + (l << 3)], bf, acc2, 0, 0, 0);
      acc3 = __builtin_amdgcn_mfma_f32_16x16x32_bf16(*(const short8v*)&asb[ks * 2048 + 3 * 512 + (l << 3)], bf, acc3, 0, 0, 0);
    }
    asm volatile("" ::: "memory");
    __builtin_amdgcn_s_barrier();
  }

  const int col = n0 + (w << 4) + (l & 15);
  const float bv = bias ? bias[col] : 0.0f;
  f32x4 accs[4] = {acc0, acc1, acc2, acc3};
  float vals[4][4];
  #pragma unroll
  for (int mb = 0; mb < 4; ++mb) {
    #pragma unroll
    for (int r = 0; r < 4; ++r) {
      int row = (mb << 4) + ((l >> 4) << 2) + r;
      float v = accs[mb][r] + bv;
      vals[mb][r] = v;
      C[(size_t)row * ldc + col] = v;
    }
  }

  if (PARTIALS) {
    #pragma unroll
    for (int mb = 0; mb < 4; ++mb) {
      #pragma unroll
      for (int r = 0; r < 4; ++r) {
        float v = vals[mb][r];
        float m = v;
        #pragma unroll
        for (int d = 1; d < 16; d <<= 1) m = fmaxf(m, __shfl_xor(m, d));
        float e = __expf(v - m);
        #pragma unroll
        for (int d = 1; d < 16; d <<= 1) e += __shfl_xor(e, d);
        if ((l & 15) == 0) {
          int row = (mb << 4) + ((l >> 4) << 2) + r;
          sm.Pm[w][row] = m;
          sm.Pl[w][row] = e;
        }
      }
    }
    __syncthreads();
    if (tid < 64) {
      float M = sm.Pm[0][tid];
      M = fmaxf(M, sm.Pm[1][tid]); M = fmaxf(M, sm.Pm[2][tid]); M = fmaxf(M, sm.Pm[3][tid]);
      float L = sm.Pl[0][tid] * __expf(sm.Pm[0][tid] - M)
              + sm.Pl[1][tid] * __expf(sm.Pm[1][tid] - M)
              + sm.Pl[2][tid] * __expf(sm.Pm[2][tid] - M)
              + sm.Pl[3][tid] * __expf(sm.Pm[3][tid] - M);
      pm[(size_t)pmb * 64 + tid] = M;
      pl[(size_t)pmb * 64 + tid] = L;
    }
    __syncthreads();
  }
}

// ============ legacy (R1-verified) f32-staging GEMM (prep + fallback) ======
__global__ __launch_bounds__(256) void gemm64_mfma(
    const float* __restrict__ A, int lda,
    const void* __restrict__ Wa, int ldwa,
    const void* __restrict__ Wb, int ldwb, int ksplit,
    const float* __restrict__ bias1, const float* __restrict__ bias2,
    float* __restrict__ C, size_t ldc,
    int K, int wbf16,
    float* __restrict__ pm, float* __restrict__ pl)
{
  __shared__ unsigned short As[2048];
  __shared__ unsigned short Bs[2048];
  __shared__ float Pm[4][64];
  __shared__ float Pl[4][64];

  const int tid  = threadIdx.x;
  const int lane = tid & 63;
  const int w    = tid >> 6;
  const int n0   = blockIdx.x * 64;

  f32x4 acc0 = {0.f,0.f,0.f,0.f}, acc1 = {0.f,0.f,0.f,0.f};
  f32x4 acc2 = {0.f,0.f,0.f,0.f}, acc3 = {0.f,0.f,0.f,0.f};

  for (int k0 = 0; k0 < K; k0 += 32) {
    #pragma unroll
    for (int ss = 0; ss < 2; ++ss) {
      int s  = tid + ss * 256;
      int r  = s >> 3;
      int kq = s & 7;
      int kL = kq * 4;
      int kg = k0 + kL;
      const float* ap = A + (size_t)r * lda + kg;
      float4 av = *(const float4*)ap;
      ushort4 au;
      au.x = f2bf(av.x); au.y = f2bf(av.y); au.z = f2bf(av.z); au.w = f2bf(av.w);
      int dst = ((r >> 4) << 9) + ((kL >> 3) << 7) + ((r & 15) << 3) + (kL & 7);
      *(ushort4*)&As[dst] = au;
      int n = n0 + r;
      ushort4 bu;
      if (wbf16) {
        const unsigned short* wpp = (kg < ksplit)
          ? (const unsigned short*)Wa + (size_t)n * ldwa + kg
          : (const unsigned short*)Wb + (size_t)n * ldwb + (kg - ksplit);
        bu = *(const ushort4*)wpp;
      } else {
        const float* wpp = (kg < ksplit)
          ? (const float*)Wa + (size_t)n * ldwa + kg
          : (const float*)Wb + (size_t)n * ldwb + (kg - ksplit);
        float4 wv = *(const float4*)wpp;
        bu.x = f2bf(wv.x); bu.y = f2bf(wv.y); bu.z = f2bf(wv.z); bu.w = f2bf(wv.w);
      }
      *(ushort4*)&Bs[dst] = bu;
    }
    __syncthreads();
    short8v bf = *(const short8v*)&Bs[(w << 9) + (lane << 3)];
    short8v a0 = *(const short8v*)&As[(0 << 9) + (lane << 3)];
    short8v a1 = *(const short8v*)&As[(1 << 9) + (lane << 3)];
    short8v a2 = *(const short8v*)&As[(2 << 9) + (lane << 3)];
    short8v a3 = *(const short8v*)&As[(3 << 9) + (lane << 3)];
    acc0 = __builtin_amdgcn_mfma_f32_16x16x32_bf16(a0, bf, acc0, 0, 0, 0);
    acc1 = __builtin_amdgcn_mfma_f32_16x16x32_bf16(a1, bf, acc1, 0, 0, 0);
    acc2 = __builtin_amdgcn_mfma_f32_16x16x32_bf16(a2, bf, acc2, 0, 0, 0);
    acc3 = __builtin_amdgcn_mfma_f32_16x16x32_bf16(a3, bf, acc3, 0, 0, 0);
    __syncthreads();
  }

  const int col = n0 + (w << 4) + (lane & 15);
  const float bv = (bias1 ? bias1[col] : 0.0f) + (bias2 ? bias2[col] : 0.0f);
  f32x4 accs[4] = {acc0, acc1, acc2, acc3};
  float vals[4][4];
  #pragma unroll
  for (int mb = 0; mb < 4; ++mb) {
    #pragma unroll
    for (int r = 0; r < 4; ++r) {
      int row = (mb << 4) + ((lane >> 4) << 2) + r;
      float v = accs[mb][r] + bv;
      vals[mb][r] = v;
      C[(size_t)row * ldc + col] = v;
    }
  }

  if (pm) {
    #pragma unroll
    for (int mb = 0; mb < 4; ++mb) {
      #pragma unroll
      for (int r = 0; r < 4; ++r) {
        float v = vals[mb][r];
        float m = v;
        #pragma unroll
        for (int d = 1; d < 16; d <<= 1) m = fmaxf(m, __shfl_xor(m, d));
        float e = __expf(v - m);
        #pragma unroll
        for (int d = 1; d < 16; d <<= 1) e += __shfl_xor(e, d);
        if ((lane & 15) == 0) {
          int row = (mb << 4) + ((lane >> 4) << 2) + r;
          Pm[w][row] = m;
          Pl[w][row] = e;
        }
      }
    }
    __syncthreads();
    if (tid < 64) {
      float M = Pm[0][tid];
      M = fmaxf(M, Pm[1][tid]); M = fmaxf(M, Pm[2][tid]); M = fmaxf(M, Pm[3][tid]);
      float L = Pl[0][tid] * __expf(Pm[0][tid] - M)
              + Pl[1][tid] * __expf(Pm[1][tid] - M)
              + Pl[2][tid] * __expf(Pm[2][tid] - M)
              + Pl[3][tid] * __expf(Pm[3][tid] - M);
      pm[(size_t)blockIdx.x * 64 + tid] = M;
      pl[(size_t)blockIdx.x * 64 + tid] = L;
    }
  }
}

// f32 -> bf16 bulk convert
__global__ __launch_bounds__(256) void k_f32_to_bf16(
    const float* __restrict__ src, unsigned short* __restrict__ dst, int n) {
  int i0 = (blockIdx.x * 256 + threadIdx.x) * 8;
  int stride = gridDim.x * 256 * 8;
  for (int i = i0; i < n; i += stride) {
    float4 a = *(const float4*)(src + i);
    float4 c = *(const float4*)(src + i + 4);
    ushort4 u1, u2;
    u1.x = f2bf(a.x); u1.y = f2bf(a.y); u1.z = f2bf(a.z); u1.w = f2bf(a.w);
    u2.x = f2bf(c.x); u2.y = f2bf(c.y); u2.z = f2bf(c.z); u2.w = f2bf(c.w);
    *(ushort4*)(dst + i)     = u1;
    *(ushort4*)(dst + i + 4) = u2;
  }
}

// normalize one 4096-elem unit of lp(t')
DEV void norm_apply(int j, float* __restrict__ lp_base, const float* __restrict__ logZ, int tid) {
  #pragma unroll
  for (int q = 0; q < 4; ++q) {
    size_t e = (size_t)j * 4096 + q * 1024 + tid * 4;
    int b = (int)(e / 32000);
    int r = (int)(e - (size_t)b * 32000);
    float4* p = (float4*)(lp_base + (size_t)b * T * V + r);
    float z = logZ[b];
    float4 v = *p;
    v.x -= z; v.y -= z; v.z -= z; v.w -= z;
    *p = v;
  }
}

// logZ reduce over 500 tiles for batch b (pm layout [tile][64])
DEV void logz_reduce(LogZSm& z, const float* __restrict__ pm,
                     const float* __restrict__ pl, int b, float* __restrict__ dst) {
  const int tid = threadIdx.x;
  float m1 = pm[(size_t)tid * 64 + b];
  float l1 = pl[(size_t)tid * 64 + b];
  int j2 = tid + 256;
  if (j2 < NBL) {
    float m2 = pm[(size_t)j2 * 64 + b], l2 = pl[(size_t)j2 * 64 + b];
    float M = fmaxf(m1, m2);
    l1 = l1 * __expf(m1 - M) + l2 * __expf(m2 - M);
    m1 = M;
  }
  z.rm[tid] = m1; z.rl[tid] = l1;
  __syncthreads();
  for (int off = 128; off > 0; off >>= 1) {
    if (tid < off) {
      float ma = z.rm[tid], mb2 = z.rm[tid + off];
      float M = fmaxf(ma, mb2);
      z.rl[tid] = z.rl[tid] * __expf(ma - M) + z.rl[tid + off] * __expf(mb2 - M);
      z.rm[tid] = M;
    }
    __syncthreads();
  }
  if (tid == 0) dst[b] = z.rm[0] + __logf(z.rl[0]);
}

// ============ K1: fused cell(t-1) + qW1 + scores/softmax/ctx/xbuf ==========
// blocks [0,64): batch b.  blocks [64,64+nlz): logZ(t-2).
__global__ __launch_bounds__(256) void k_step_attn(
    const float* __restrict__ gpart, const float* __restrict__ b_ih,
    const float* __restrict__ b_hh, float* __restrict__ cbuf,
    const float* __restrict__ h0f,
    unsigned short* __restrict__ hhistb,
    const unsigned short* __restrict__ w1b, const float* __restrict__ b1,
    const float* __restrict__ keys, const float* __restrict__ Vw,
    const float* __restrict__ Vb,
    const float* __restrict__ enc, const float* __restrict__ emb,
    const int* __restrict__ tok,
    unsigned short* __restrict__ xbufb, float* __restrict__ attn_out, int t,
    const float* __restrict__ pmv, const float* __restrict__ plv,
    float* __restrict__ logZ)
{
  __shared__ K1U u;
  const int tid = threadIdx.x;
  const int bx = blockIdx.x;

  if (bx >= 64) {                 // logZ(t-2) ride
    logz_reduce(u.z, pmv, plv, bx - 64, logZ);
    return;
  }

  const int b = bx;
  const int h0i = tid * 4;

  // ---- phase A: cell(t-1) -> h_t (or bridge h0 at t==0) ----
  if (t == 0) {
    float4 h4 = *(const float4*)(h0f + (size_t)b * H + h0i);
    *(float4*)&u.a.hv[h0i] = h4;
  } else {
    float gi[4], gf[4], gg[4], go[4];
    #pragma unroll
    for (int j = 0; j < 4; ++j) {
      gi[j] = b_ih[h0i + j]         + b_hh[h0i + j];
      gf[j] = b_ih[H + h0i + j]     + b_hh[H + h0i + j];
      gg[j] = b_ih[2 * H + h0i + j] + b_hh[2 * H + h0i + j];
      go[j] = b_ih[3 * H + h0i + j] + b_hh[3 * H + h0i + j];
    }
    #pragma unroll
    for (int p = 0; p < 6; ++p) {
      const float* g = gpart + (size_t)p * B * H4 + (size_t)b * H4;
      float4 a0 = *(const float4*)(g + h0i);
      float4 a1 = *(const float4*)(g + H + h0i);
      float4 a2 = *(const float4*)(g + 2 * H + h0i);
      float4 a3 = *(const float4*)(g + 3 * H + h0i);
      gi[0] += a0.x; gi[1] += a0.y; gi[2] += a0.z; gi[3] += a0.w;
      gf[0] += a1.x; gf[1] += a1.y; gf[2] += a1.z; gf[3] += a1.w;
      gg[0] += a2.x; gg[1] += a2.y; gg[2] += a2.z; gg[3] += a2.w;
      go[0] += a3.x; go[1] += a3.y; go[2] += a3.z; go[3] += a3.w;
    }
    float4 c4 = *(const float4*)(cbuf + (size_t)b * H + h0i);
    float cc[4] = {c4.x, c4.y, c4.z, c4.w};
    float hh[4];
    ushort4 hb;
    #pragma unroll
    for (int j = 0; j < 4; ++j) {
      float c = fast_sig(gf[j]) * cc[j] + fast_sig(gi[j]) * fast_tanh(gg[j]);
      hh[j] = fast_sig(go[j]) * fast_tanh(c);
      cc[j] = c;
    }
    c4.x = cc[0]; c4.y = cc[1]; c4.z = cc[2]; c4.w = cc[3];
    *(float4*)(cbuf + (size_t)b * H + h0i) = c4;
    float4 h4 = {hh[0], hh[1], hh[2], hh[3]};
    *(float4*)&u.a.hv[h0i] = h4;
    hb.x = f2bf(hh[0]); hb.y = f2bf(hh[1]); hb.z = f2bf(hh[2]); hb.w = f2bf(hh[3]);
    *(ushort4*)(hhistb + (size_t)t * BH + (size_t)b * H + h0i) = hb;
  }
  __syncthreads();

  // ---- phase B: q = W1 @ h + b1 (VALU, rows tid + r*256) ----
  {
    float acc0 = 0.f, acc1 = 0.f, acc2 = 0.f, acc3 = 0.f;
    for (int ck = 0; ck < 128; ++ck) {
      float4 ha = *(const float4*)&u.a.hv[ck * 8];
      float4 hb2 = *(const float4*)&u.a.hv[ck * 8 + 4];
      uint4 w0 = *(const uint4*)(w1b + (size_t)(0 * 256 + tid) * H + ck * 8);
      uint4 w1 = *(const uint4*)(w1b + (size_t)(1 * 256 + tid) * H + ck * 8);
      uint4 w2 = *(const uint4*)(w1b + (size_t)(2 * 256 + tid) * H + ck * 8);
      uint4 w3 = *(const uint4*)(w1b + (size_t)(3 * 256 + tid) * H + ck * 8);
      acc0 += bfl(w0.x)*ha.x + bfh(w0.x)*ha.y + bfl(w0.y)*ha.z + bfh(w0.y)*ha.w
            + bfl(w0.z)*hb2.x + bfh(w0.z)*hb2.y + bfl(w0.w)*hb2.z + bfh(w0.w)*hb2.w;
      acc1 += bfl(w1.x)*ha.x + bfh(w1.x)*ha.y + bfl(w1.y)*ha.z + bfh(w1.y)*ha.w
            + bfl(w1.z)*hb2.x + bfh(w1.z)*hb2.y + bfl(w1.w)*hb2.z + bfh(w1.w)*hb2.w;
      acc2 += bfl(w2.x)*ha.x + bfh(w2.x)*ha.y + bfl(w2.y)*ha.z + bfh(w2.y)*ha.w
            + bfl(w2.z)*hb2.x + bfh(w2.z)*hb2.y + bfl(w2.w)*hb2.z + bfh(w2.w)*hb2.w;
      acc3 += bfl(w3.x)*ha.x + bfh(w3.x)*ha.y + bfl(w3.y)*ha.z + bfh(w3.y)*ha.w
            + bfl(w3.z)*hb2.x + bfh(w3.z)*hb2.y + bfl(w3.w)*hb2.z + bfh(w3.w)*hb2.w;
    }
    __syncthreads();            // hv reads done before qw write (union-safe: distinct arrays)
    u.a.qw[0 * 256 + tid] = acc0 + b1[0 * 256 + tid];
    u.a.qw[1 * 256 + tid] = acc1 + b1[1 * 256 + tid];
    u.a.qw[2 * 256 + tid] = acc2 + b1[2 * 256 + tid];
    u.a.qw[3 * 256 + tid] = acc3 + b1[3 * 256 + tid];
  }
  __syncthreads();

  // ---- phase C: scores + softmax + ctx + xbuf ----
  const int w = tid >> 6, lane = tid & 63;
  {
    float vwr[16], qr[16];
    #pragma unroll
    for (int uu = 0; uu < 16; ++uu) {
      int h = lane + (uu << 6);
      vwr[uu] = Vw[h];
      qr[uu]  = u.a.qw[h];
    }
    for (int si = 0; si < 32; ++si) {
      int sg = w * 32 + si;
      const float* kp = keys + (size_t)sg * H;
      float p = 0.0f;
      #pragma unroll
      for (int uu = 0; uu < 16; ++uu) {
        p += vwr[uu] * fast_tanh(qr[uu] + kp[lane + (uu << 6)]);
      }
      #pragma unroll
      for (int d = 1; d < 64; d <<= 1) p += __shfl_xor(p, d);
      if (lane == 0) u.a.sc[sg] = p + Vb[0];
    }
  }
  __syncthreads();
  if (tid < 64) {
    float a0 = u.a.sc[tid], a1 = u.a.sc[tid + 64];
    float m = fmaxf(a0, a1);
    #pragma unroll
    for (int d = 1; d < 64; d <<= 1) m = fmaxf(m, __shfl_xor(m, d));
    float e0 = __expf(a0 - m), e1 = __expf(a1 - m);
    float sum = e0 + e1;
    #pragma unroll
    for (int d = 1; d < 64; d <<= 1) sum += __shfl_xor(sum, d);
    float v0 = e0 / sum, v1 = e1 / sum;
    u.a.al[tid] = v0; u.a.al[tid + 64] = v1;
    attn_out[((size_t)t * B + b) * S + tid]      = v0;
    attn_out[((size_t)t * B + b) * S + tid + 64] = v1;
  }
  __syncthreads();

  float4 acc = {0, 0, 0, 0};
  const float* ep = enc + (size_t)b * S * H + h0i;
  for (int sx = 0; sx < S; ++sx) {
    float4 e4 = *(const float4*)(ep + (size_t)sx * H);
    float av = u.a.al[sx];
    acc.x += av * e4.x; acc.y += av * e4.y; acc.z += av * e4.z; acc.w += av * e4.w;
  }
  int token = tok[b * T + t];
  float4 em = *(const float4*)(emb + (size_t)token * H + h0i);
  float4 hv4 = *(const float4*)&u.a.hv[h0i];
  ushort4 ue, uc, uh;
  ue.x = f2bf(em.x);  ue.y = f2bf(em.y);  ue.z = f2bf(em.z);  ue.w = f2bf(em.w);
  uc.x = f2bf(acc.x); uc.y = f2bf(acc.y); uc.z = f2bf(acc.z); uc.w = f2bf(acc.w);
  uh.x = f2bf(hv4.x); uh.y = f2bf(hv4.y); uh.z = f2bf(hv4.z); uh.w = f2bf(hv4.w);
  unsigned short* xb = xbufb + (size_t)b * KX;
  *(ushort4*)(xb + h0i)         = ue;
  *(ushort4*)(xb + H + h0i)     = uc;
  *(ushort4*)(xb + 2 * H + h0i) = uh;
}

// ============ K2: gates split-K x6 + ride logits(t-1) + norm(t-2) ==========
__global__ __launch_bounds__(256) void k_step_gates(
    const unsigned short* __restrict__ xbufb,
    const unsigned short* __restrict__ wihb,
    const unsigned short* __restrict__ whhb,
    float* __restrict__ gpart,
    const unsigned short* __restrict__ hbt,   // h_t (for logits(t-1))
    const unsigned short* __restrict__ outWb, const float* __restrict__ outb,
    float* __restrict__ lp_prev, float* __restrict__ pmv, float* __restrict__ plv,
    int nlg,
    float* __restrict__ lp_norm, const float* __restrict__ logZ, int ngates)
{
  __shared__ GemmSm sm;
  const int bx = blockIdx.x;
  if (bx < ngates) {
    const int kc = bx >> 6, nb = bx & 63;
    const unsigned short* A;
    const unsigned short* W;
    int ldw;
    if (kc < 4) { A = xbufb + kc * 512; W = wihb + kc * 512; ldw = 2 * H; }
    else        { A = xbufb + 2048 + (kc - 4) * 512; W = whhb + (kc - 4) * 512; ldw = H; }
    gemm_body2<false>(sm, A, KX, W, ldw, 512, nb * 64,
                      gpart + (size_t)kc * B * H4, (size_t)H4, nullptr, nullptr, nullptr, 0);
  } else if (bx < ngates + nlg) {
    const int tile = bx - ngates;
    gemm_body2<true>(sm, hbt, H, outWb, H, H, tile * 64,
                     lp_prev, (size_t)T * V, outb, pmv, plv, tile);
  } else {
    norm_apply(bx - ngates - nlg, lp_norm, logZ, threadIdx.x);
  }
}

// ============ tail kernels ============
// cell(T-1) -> h_T (out_h/out_c + hhistb slot T) + ride logZ(T-2)
__global__ __launch_bounds__(256) void k_celltail(
    const float* __restrict__ gpart, const float* __restrict__ b_ih,
    const float* __restrict__ b_hh, const float* __restrict__ cbuf,
    float* __restrict__ out_h, float* __restrict__ out_c,
    unsigned short* __restrict__ hb_T,
    const float* __restrict__ pmv, const float* __restrict__ plv,
    float* __restrict__ logZ)
{
  __shared__ LogZSm z;
  const int bx = blockIdx.x;
  const int tid = threadIdx.x;
  if (bx < 256) {
    const int idx = bx * 256 + tid;
    const int b = idx >> 10, h = idx & 1023;
    float gi = b_ih[h]         + b_hh[h];
    float gf = b_ih[H + h]     + b_hh[H + h];
    float gg = b_ih[2 * H + h] + b_hh[2 * H + h];
    float go = b_ih[3 * H + h] + b_hh[3 * H + h];
    #pragma unroll
    for (int p = 0; p < 6; ++p) {
      const float* g = gpart + (size_t)p * B * H4 + (size_t)b * H4;
      gi += g[h]; gf += g[H + h]; gg += g[2 * H + h]; go += g[3 * H + h];
    }
    float c = fast_sig(gf) * cbuf[idx] + fast_sig(gi) * fast_tanh(gg);
    float hv = fast_sig(go) * fast_tanh(c);
    out_h[idx] = hv;
    out_c[idx] = c;
    hb_T[idx] = f2bf(hv);
  } else {
    logz_reduce(z, pmv, plv, bx - 256, logZ);
  }
}

__global__ __launch_bounds__(256) void k_logz_solo(
    const float* __restrict__ pmv, const float* __restrict__ plv,
    float* __restrict__ logZ)
{
  __shared__ LogZSm z;
  logz_reduce(z, pmv, plv, blockIdx.x, logZ);
}

__global__ __launch_bounds__(256) void k_norm_solo(
    float* __restrict__ lp_base, const float* __restrict__ logZ)
{
  norm_apply(blockIdx.x, lp_base, logZ, threadIdx.x);
}

// ================= legacy fallback kernels (R1-proven) =====================
__global__ __launch_bounds__(256) void k_scores_leg(
    const float* __restrict__ qW1, const float* __restrict__ keys,
    const float* __restrict__ Vw, const float* __restrict__ Vb,
    float* __restrict__ scores)
{
  __shared__ float qw[H];
  __shared__ float vw[H];
  const int b  = blockIdx.x >> 2;
  const int sq = blockIdx.x & 3;
  const int tid = threadIdx.x;
  #pragma unroll
  for (int i = 0; i < 4; ++i) {
    qw[tid + i * 256] = qW1[b * H + tid + i * 256];
    vw[tid + i * 256] = Vw[tid + i * 256];
  }
  __syncthreads();
  const int w = tid >> 6, lane = tid & 63;
  #pragma unroll
  for (int si = 0; si < 8; ++si) {
    int sg = sq * 32 + w * 8 + si;
    const float* kp = keys + (size_t)sg * H;
    float p = 0.0f;
    #pragma unroll
    for (int u = 0; u < 16; ++u) {
      int h = lane + (u << 6);
      p += vw[h] * fast_tanh(qw[h] + kp[h]);
    }
    #pragma unroll
    for (int d = 1; d < 64; d <<= 1) p += __shfl_xor(p, d);
    if (lane == 0) scores[b * S + sg] = p + Vb[0];
  }
}

__global__ __launch_bounds__(256) void k_attn_ctx_leg(
    const float* __restrict__ scores, const float* __restrict__ enc,
    const float* __restrict__ emb, const int* __restrict__ tok,
    const float* __restrict__ hcur, float* __restrict__ xbuf,
    float* __restrict__ attn_out, int t)
{
  __shared__ float al[S];
  __shared__ float wred[4];
  const int b   = blockIdx.x >> 2;
  const int hq  = blockIdx.x & 3;
  const int tid = threadIdx.x;

  float sv = (tid < S) ? scores[b * S + tid] : -1e30f;
  float m = sv;
  #pragma unroll
  for (int d = 1; d < 64; d <<= 1) m = fmaxf(m, __shfl_xor(m, d));
  if ((tid & 63) == 0) wred[tid >> 6] = m;
  __syncthreads();
  m = fmaxf(fmaxf(wred[0], wred[1]), fmaxf(wred[2], wred[3]));
  float e = (tid < S) ? __expf(sv - m) : 0.0f;
  float ssum = e;
  #pragma unroll
  for (int d = 1; d < 64; d <<= 1) ssum += __shfl_xor(ssum, d);
  __syncthreads();
  if ((tid & 63) == 0) wred[tid >> 6] = ssum;
  __syncthreads();
  float tot = wred[0] + wred[1] + wred[2] + wred[3];
  float a = e / tot;
  if (tid < S) {
    al[tid] = a;
    if (hq == 0) attn_out[((size_t)t * B + b) * S + tid] = a;
  }
  __syncthreads();

  const int h = hq * 256 + tid;
  float acc = 0.0f;
  const float* ep = enc + (size_t)b * S * H + h;
  #pragma unroll 4
  for (int s = 0; s < S; ++s) acc += al[s] * ep[(size_t)s * H];

  int token = tok[b * T + t];
  xbuf[b * KX + h]         = emb[(size_t)token * H + h];
  xbuf[b * KX + H + h]     = acc;
  xbuf[b * KX + 2 * H + h] = hcur[b * H + h];
}

__global__ __launch_bounds__(256) void k_cell_leg(
    const float* __restrict__ gates, const float* __restrict__ cprev,
    float* __restrict__ hnew, float* __restrict__ cnew,
    float* __restrict__ hout, float* __restrict__ cout, int last)
{
  int idx = blockIdx.x * 256 + threadIdx.x;
  int b = idx >> 10, h = idx & 1023;
  const float* g = gates + (size_t)b * H4;
  float gi = g[h], gf = g[H + h], gg = g[2 * H + h], go = g[3 * H + h];
  float c = fast_sig(gf) * cprev[idx] + fast_sig(gi) * fast_tanh(gg);
  float hv = fast_sig(go) * fast_tanh(c);
  cnew[idx] = c;
  hnew[idx] = hv;
  if (last) { hout[idx] = hv; cout[idx] = c; }
}

__global__ __launch_bounds__(256) void k_norm_leg(
    const float* __restrict__ pm, const float* __restrict__ pl,
    float* __restrict__ lp, int t)
{
  __shared__ float rm[256], rl[256];
  const int bx = blockIdx.x;
  const int b  = bx / 125;
  const int ch = bx % 125;
  const int tid = threadIdx.x;

  float m1 = pm[(size_t)tid * 64 + b];
  float l1 = pl[(size_t)tid * 64 + b];
  int nb2 = tid + 256;
  if (nb2 < NBL) {
    float m2 = pm[(size_t)nb2 * 64 + b];
    float l2 = pl[(size_t)nb2 * 64 + b];
    float M = fmaxf(m1, m2);
    l1 = l1 * __expf(m1 - M) + l2 * __expf(m2 - M);
    m1 = M;
  }
  rm[tid] = m1; rl[tid] = l1;
  __syncthreads();
  for (int off = 128; off > 0; off >>= 1) {
    if (tid < off) {
      float ma = rm[tid], mb = rm[tid + off];
      float M = fmaxf(ma, mb);
      rl[tid] = rl[tid] * __expf(ma - M) + rl[tid + off] * __expf(mb - M);
      rm[tid] = M;
    }
    __syncthreads();
  }
  float logZ = rm[0] + __logf(rl[0]);
  size_t base = ((size_t)b * T + t) * V + (size_t)ch * 256;
  lp[base + tid] -= logZ;
}

// ============================ host launcher ================================
static void run_legacy(void* const* d_in, void* d_out, void* d_ws, size_t ws_size,
                       hipStream_t stream)
{
  const float* enc  = (const float*)d_in[0];
  const float* eh   = (const float*)d_in[1];
  const float* ec   = (const float*)d_in[2];
  const int*   tok  = (const int*)d_in[4];
  const float* emb  = (const float*)d_in[5];
  const float* W1   = (const float*)d_in[6];
  const float* b1   = (const float*)d_in[7];
  const float* W2   = (const float*)d_in[8];
  const float* b2   = (const float*)d_in[9];
  const float* Vw   = (const float*)d_in[10];
  const float* Vb   = (const float*)d_in[11];
  const float* W_ih = (const float*)d_in[12];
  const float* W_hh = (const float*)d_in[13];
  const float* b_ih = (const float*)d_in[14];
  const float* b_hh = (const float*)d_in[15];
  const float* outW = (const float*)d_in[16];
  const float* outb = (const float*)d_in[17];
  const float* br1W = (const float*)d_in[18];
  const float* br1b = (const float*)d_in[19];
  const float* br2W = (const float*)d_in[20];
  const float* br2b = (const float*)d_in[21];

  float* out    = (float*)d_out;
  float* out_h  = out + (size_t)B * T * V;
  float* out_c  = out_h + BH;
  float* out_at = out_c + BH;

  char* wp = (char*)d_ws;
  auto alloc = [&](size_t bytes) {
    char* p = wp; wp += (bytes + 255) & ~(size_t)255; return p;
  };
  float* keysL   = (float*)alloc((size_t)S * H * 4);
  float* hbuf0   = (float*)alloc((size_t)BH * 4);
  float* hbuf1   = (float*)alloc((size_t)BH * 4);
  float* cbuf0L  = (float*)alloc((size_t)BH * 4);
  float* cbuf1L  = (float*)alloc((size_t)BH * 4);
  float* qW1vL   = (float*)alloc((size_t)BH * 4);
  float* scoresL = (float*)alloc((size_t)B * S * 4);
  float* xbuf    = (float*)alloc((size_t)B * KX * 4);
  float* gates   = (float*)alloc((size_t)B * H4 * 4);
  float* pmvL    = (float*)alloc((size_t)NBL * 64 * 4);
  float* plvL    = (float*)alloc((size_t)NBL * 64 * 4);
  unsigned short* outWbL = (unsigned short*)alloc((size_t)V * H * 2);
  size_t need_out = (size_t)(wp - (char*)d_ws);
  unsigned short* wihbL = (unsigned short*)alloc((size_t)H4 * 2 * H * 2);
  unsigned short* whhbL = (unsigned short*)alloc((size_t)H4 * H * 2);
  unsigned short* w1bL  = (unsigned short*)alloc((size_t)H * H * 2);
  size_t need_all = (size_t)(wp - (char*)d_ws);

  const bool cvtOut = ws_size >= need_out;
  const bool cvtAll = ws_size >= need_all;

  if (cvtOut) k_f32_to_bf16<<<4096, 256, 0, stream>>>(outW, outWbL, V * H);
  if (cvtAll) {
    k_f32_to_bf16<<<2048, 256, 0, stream>>>(W_ih, wihbL, H4 * 2 * H);
    k_f32_to_bf16<<<1024, 256, 0, stream>>>(W_hh, whhbL, H4 * H);
    k_f32_to_bf16<<<256, 256, 0, stream>>>(W1, w1bL, H * H);
  }

  gemm64_mfma<<<16, 256, 0, stream>>>(enc,          H, W2, H, W2, H, H, b2, nullptr, keysL,          H, H, 0, nullptr, nullptr);
  gemm64_mfma<<<16, 256, 0, stream>>>(enc + 64 * H, H, W2, H, W2, H, H, b2, nullptr, keysL + 64 * H, H, H, 0, nullptr, nullptr);
  gemm64_mfma<<<16, 256, 0, stream>>>(eh, H, br1W, H, br1W, H, H, br1b, nullptr, hbuf0, H, H, 0, nullptr, nullptr);
  gemm64_mfma<<<16, 256, 0, stream>>>(ec, H, br2W, H, br2W, H, H, br2b, nullptr, cbuf0L, H, H, 0, nullptr, nullptr);

  float* hb[2] = {hbuf0, hbuf1};
  float* cb[2] = {cbuf0L, cbuf1L};

  for (int t = 0; t < T; ++t) {
    const int cur = t & 1, nxt = cur ^ 1;
    if (cvtAll)
      gemm64_mfma<<<16, 256, 0, stream>>>(hb[cur], H, w1bL, H, w1bL, H, H, b1, nullptr, qW1vL, H, H, 1, nullptr, nullptr);
    else
      gemm64_mfma<<<16, 256, 0, stream>>>(hb[cur], H, W1, H, W1, H, H, b1, nullptr, qW1vL, H, H, 0, nullptr, nullptr);
    k_scores_leg<<<256, 256, 0, stream>>>(qW1vL, keysL, Vw, Vb, scoresL);
    k_attn_ctx_leg<<<256, 256, 0, stream>>>(scoresL, enc, emb, tok, hb[cur], xbuf, out_at, t);
    if (cvtAll)
      gemm64_mfma<<<64, 256, 0, stream>>>(xbuf, KX, wihbL, 2 * H, whhbL, H, 2 * H, b_ih, b_hh, gates, H4, KX, 1, nullptr, nullptr);
    else
      gemm64_mfma<<<64, 256, 0, stream>>>(xbuf, KX, W_ih, 2 * H, W_hh, H, 2 * H, b_ih, b_hh, gates, H4, KX, 0, nullptr, nullptr);
    k_cell_leg<<<256, 256, 0, stream>>>(gates, cb[cur], hb[nxt], cb[nxt], out_h, out_c, t == T - 1);
    if (cvtOut)
      gemm64_mfma<<<NBL, 256, 0, stream>>>(hb[nxt], H, outWbL, H, outWbL, H, H, outb, nullptr, out + (size_t)t * V, (size_t)T * V, H, 1, pmvL, plvL);
    else
      gemm64_mfma<<<NBL, 256, 0, stream>>>(hb[nxt], H, outW, H, outW, H, H, outb, nullptr, out + (size_t)t * V, (size_t)T * V, H, 0, pmvL, plvL);
    k_norm_leg<<<64 * 125, 256, 0, stream>>>(pmvL, plvL, out, t);
  }
}

extern "C" void kernel_launch(void* const* d_in, const int* in_sizes, int n_in,
                              void* d_out, int out_size, void* d_ws, size_t ws_size,
                              hipStream_t stream)
{
  (void)in_sizes; (void)n_in; (void)out_size;
  const float* enc  = (const float*)d_in[0];
  const float* eh   = (const float*)d_in[1];
  const float* ec   = (const float*)d_in[2];
  const int*   tok  = (const int*)d_in[4];
  const float* emb  = (const float*)d_in[5];
  const float* W1   = (const float*)d_in[6];
  const float* b1   = (const float*)d_in[7];
  const float* W2   = (const float*)d_in[8];
  const float* b2   = (const float*)d_in[9];
  const float* Vw   = (const float*)d_in[10];
  const float* Vb   = (const float*)d_in[11];
  const float* W_ih = (const float*)d_in[12];
  const float* W_hh = (const float*)d_in[13];
  const float* b_ih = (const float*)d_in[14];
  const float* b_hh = (const float*)d_in[15];
  const float* outW = (const float*)d_in[16];
  const float* outb = (const float*)d_in[17];
  const float* br1W = (const float*)d_in[18];
  const float* br1b = (const float*)d_in[19];
  const float* br2W = (const float*)d_in[20];
  const float* br2b = (const float*)d_in[21];

  float* out    = (float*)d_out;
  float* out_lp = out;
  float* out_h  = out + (size_t)B * T * V;
  float* out_c  = out_h + BH;
  float* out_at = out_c + BH;

  char* wp = (char*)d_ws;
  auto alloc = [&](size_t bytes) {
    char* p = wp; wp += (bytes + 255) & ~(size_t)255; return p;
  };
  float* keys   = (float*)alloc((size_t)S * H * 4);
  float* cbuf   = (float*)alloc((size_t)BH * 4);
  float* h0f    = (float*)alloc((size_t)BH * 4);
  unsigned short* xbufb = (unsigned short*)alloc((size_t)B * KX * 2);
  float* gpart  = (float*)alloc((size_t)6 * B * H4 * 4);
  float* pmv    = (float*)alloc((size_t)NBL * 64 * 4);
  float* plv    = (float*)alloc((size_t)NBL * 64 * 4);
  float* logZ   = (float*)alloc((size_t)B * 4);
  unsigned short* hhistb = (unsigned short*)alloc((size_t)(T + 1) * BH * 2);
  unsigned short* w1b  = (unsigned short*)alloc((size_t)H * H * 2);
  unsigned short* wihb = (unsigned short*)alloc((size_t)H4 * 2 * H * 2);
  unsigned short* whhb = (unsigned short*)alloc((size_t)H4 * H * 2);
  unsigned short* outWb = (unsigned short*)alloc((size_t)V * H * 2);
  size_t need_fast = (size_t)(wp - (char*)d_ws);

  if (ws_size < need_fast) {
    run_legacy(d_in, d_out, d_ws, ws_size, stream);
    return;
  }

  // ---- prep ----
  k_f32_to_bf16<<<2048, 256, 0, stream>>>(W_ih, wihb, H4 * 2 * H);
  k_f32_to_bf16<<<1024, 256, 0, stream>>>(W_hh, whhb, H4 * H);
  k_f32_to_bf16<<<256, 256, 0, stream>>>(W1, w1b, H * H);
  k_f32_to_bf16<<<4096, 256, 0, stream>>>(outW, outWb, V * H);

  gemm64_mfma<<<16, 256, 0, stream>>>(enc,          H, W2, H, W2, H, H, b2, nullptr, keys,          H, H, 0, nullptr, nullptr);
  gemm64_mfma<<<16, 256, 0, stream>>>(enc + 64 * H, H, W2, H, W2, H, H, b2, nullptr, keys + 64 * H, H, H, 0, nullptr, nullptr);
  gemm64_mfma<<<16, 256, 0, stream>>>(eh, H, br1W, H, br1W, H, H, br1b, nullptr, h0f, H, H, 0, nullptr, nullptr);
  gemm64_mfma<<<16, 256, 0, stream>>>(ec, H, br2W, H, br2W, H, H, br2b, nullptr, cbuf, H, H, 0, nullptr, nullptr);
  k_f32_to_bf16<<<32, 256, 0, stream>>>(h0f, hhistb, BH);    // slot 0

  // ---- 32 steps x 2 launches, with logits/logZ/norm riding ----
  for (int t = 0; t < T; ++t) {
    const int nlz = (t >= 2) ? 64 : 0;
    k_step_attn<<<64 + nlz, 256, 0, stream>>>(
        gpart, b_ih, b_hh, cbuf, h0f, hhistb, w1b, b1, keys, Vw, Vb,
        enc, emb, tok, xbufb, out_at, t, pmv, plv, logZ);   // rides logZ(t-2)
    const int nlg   = (t >= 1) ? NBL : 0;
    const int nnorm = (t >= 2) ? NBL : 0;
    k_step_gates<<<384 + nlg + nnorm, 256, 0, stream>>>(
        xbufb, wihb, whhb, gpart,
        hhistb + (size_t)t * BH, outWb, outb,
        out_lp + (size_t)(t - 1) * V, pmv, plv, nlg,
        out_lp + (size_t)(t - 2) * V, logZ, 384);
  }

  // ---- tail ----
  k_celltail<<<256 + 64, 256, 0, stream>>>(
      gpart, b_ih, b_hh, cbuf, out_h, out_c,
      hhistb + (size_t)T * BH, pmv, plv, logZ);             // logZ(T-2)
  k_step_gates<<<NBL + NBL, 256, 0, stream>>>(              // logits(T-1)+norm(T-2)
      xbufb, wihb, whhb, gpart,
      hhistb + (size_t)T * BH, outWb, outb,
      out_lp + (size_t)(T - 1) * V, pmv, plv, NBL,
      out_lp + (size_t)(T - 2) * V, logZ, 0);
  k_logz_solo<<<64, 256, 0, stream>>>(pmv, plv, logZ);      // logZ(T-1)
  k_norm_solo<<<NBL, 256, 0, stream>>>(out_lp + (size_t)(T - 1) * V, logZ);
}

// Round 9
// 3662.243 us; speedup vs baseline: 1.3880x; 1.3880x over previous
//
#include <hip/hip_runtime.h>
#include <hip/hip_bf16.h>

#define DEV __device__ __forceinline__

constexpr int B = 64, S = 128, T = 32, H = 1024, V = 32000;
constexpr int H4 = 4096;          // 4*H
constexpr int KX = 3072;          // [emb | ctx | h]
constexpr int NBL = V / 64;       // 500 logits N-tiles
constexpr int BH = B * H;

using f32x4   = __attribute__((ext_vector_type(4))) float;
using short8v = __attribute__((ext_vector_type(8))) short;

DEV unsigned short f2bf(float x) {
  union { __hip_bfloat16 b; unsigned short u; } v;
  v.b = __float2bfloat16(x);
  return v.u;
}
DEV float fast_sig(float x) { return 1.0f / (1.0f + __expf(-x)); }
DEV float fast_tanh(float x) {
  float e = __expf(2.0f * x);
  return 1.0f - 2.0f / (e + 1.0f);
}

DEV void gload16(const void* g, void* l) {
  __builtin_amdgcn_global_load_lds(
      (const __attribute__((address_space(1))) void*)g,
      (__attribute__((address_space(3))) void*)l, 16, 0, 0);
}

// ---------------- LDS ----------------
struct GemmSm {
  unsigned short As[3][4096];
  unsigned short Bs[3][4096];
  float Pm[4][64];
  float Pl[4][64];
};
struct AttnSm { float qw[H]; float vw[H]; float sc[S]; float al[S]; };
struct LogZSm { float rm[256]; float rl[256]; };
union StepSm { GemmSm g; AttnSm a; LogZSm z; };

// ============ pipelined bf16 GEMM body (M=64, Ntile=64, BK=64) ============
// verified fragment layout: lane l's 16B at l*16 -> row=mb*16+(l&15),
// k=ks*32+(l>>4)*8..+7 ; 3 LDS buffers, 2-deep prefetch, counted vmcnt.
template<bool PARTIALS>
DEV void gemm_body2(GemmSm& sm,
                    const unsigned short* __restrict__ A, int lda,
                    const unsigned short* __restrict__ W, int ldw,
                    int K, int n0,
                    float* __restrict__ C, size_t ldc,
                    const float* __restrict__ bias,
                    float* __restrict__ pm, float* __restrict__ pl, int pmb)
{
  const int tid = threadIdx.x;
  const int l   = tid & 63;
  const int w   = tid >> 6;

  f32x4 acc0 = {0,0,0,0}, acc1 = {0,0,0,0}, acc2 = {0,0,0,0}, acc3 = {0,0,0,0};

  const int rA = l & 15;
  const int kq = (l >> 4) << 3;

  auto stage = [&](int k0, int buf) {
    #pragma unroll
    for (int i = 0; i < 4; ++i) {
      const int c    = (w << 2) | i;
      const int side = c >> 3;
      const int ks   = (c >> 2) & 1;
      const int mb   = c & 3;
      const int kk   = k0 + ks * 32 + kq;
      const int row  = mb * 16 + rA;
      const unsigned short* src = side
        ? W + (size_t)(n0 + row) * ldw + kk
        : A + (size_t)row * lda + kk;
      unsigned short* dst = (side ? sm.Bs[buf] : sm.As[buf]) + ks * 2048 + mb * 512;
      gload16(src, dst);
    }
  };

  const int nk = K >> 6;
  stage(0, 0);
  if (nk > 1) stage(64, 1);
  for (int kt = 0; kt < nk; ++kt) {
    const int buf = kt % 3;
    if (kt + 2 < nk) {
      stage((kt + 2) << 6, (kt + 2) % 3);
      asm volatile("s_waitcnt vmcnt(8)" ::: "memory");
    } else if (kt + 1 < nk) {
      asm volatile("s_waitcnt vmcnt(4)" ::: "memory");
    } else {
      asm volatile("s_waitcnt vmcnt(0)" ::: "memory");
    }
    __builtin_amdgcn_s_barrier();
    asm volatile("" ::: "memory");
    const unsigned short* __restrict__ asb = sm.As[buf];
    const unsigned short* __restrict__ bsb = sm.Bs[buf];
    #pragma unroll
    for (int ks = 0; ks < 2; ++ks) {
      short8v bf = *(const short8v*)&bsb[ks * 2048 + (w << 9) + (l << 3)];
      acc0 = __builtin_amdgcn_mfma_f32_16x16x32_bf16(*(const short8v*)&asb[ks * 2048 + 0 * 512 + (l << 3)], bf, acc0, 0, 0, 0);
      acc1 = __builtin_amdgcn_mfma_f32_16x16x32_bf16(*(const short8v*)&asb[ks * 2048 + 1 * 512 + (l << 3)], bf, acc1, 0, 0, 0);
      acc2 = __builtin_amdgcn_mfma_f32_16x16x32_bf16(*(const short8v*)&asb[ks * 2048 + 2 * 512 + (l << 3)], bf, acc2, 0, 0, 0);
      acc3 = __builtin_amdgcn_mfma_f32_16x16x32_bf16(*(const short8v*)&asb[ks * 2048 + 3 * 512 + (l << 3)], bf, acc3, 0, 0, 0);
    }
    asm volatile("" ::: "memory");
    __builtin_amdgcn_s_barrier();
  }

  const int col = n0 + (w << 4) + (l & 15);
  const float bv = bias ? bias[col] : 0.0f;
  f32x4 accs[4] = {acc0, acc1, acc2, acc3};
  float vals[4][4];
  #pragma unroll
  for (int mb = 0; mb < 4; ++mb) {
    #pragma unroll
    for (int r = 0; r < 4; ++r) {
      int row = (mb << 4) + ((l >> 4) << 2) + r;
      float v = accs[mb][r] + bv;
      vals[mb][r] = v;
      C[(size_t)row * ldc + col] = v;
    }
  }

  if (PARTIALS) {
    #pragma unroll
    for (int mb = 0; mb < 4; ++mb) {
      #pragma unroll
      for (int r = 0; r < 4; ++r) {
        float v = vals[mb][r];
        float m = v;
        #pragma unroll
        for (int d = 1; d < 16; d <<= 1) m = fmaxf(m, __shfl_xor(m, d));
        float e = __expf(v - m);
        #pragma unroll
        for (int d = 1; d < 16; d <<= 1) e += __shfl_xor(e, d);
        if ((l & 15) == 0) {
          int row = (mb << 4) + ((l >> 4) << 2) + r;
          sm.Pm[w][row] = m;
          sm.Pl[w][row] = e;
        }
      }
    }
    __syncthreads();
    if (tid < 64) {
      float M = sm.Pm[0][tid];
      M = fmaxf(M, sm.Pm[1][tid]); M = fmaxf(M, sm.Pm[2][tid]); M = fmaxf(M, sm.Pm[3][tid]);
      float L = sm.Pl[0][tid] * __expf(sm.Pm[0][tid] - M)
              + sm.Pl[1][tid] * __expf(sm.Pm[1][tid] - M)
              + sm.Pl[2][tid] * __expf(sm.Pm[2][tid] - M)
              + sm.Pl[3][tid] * __expf(sm.Pm[3][tid] - M);
      pm[(size_t)pmb * 64 + tid] = M;
      pl[(size_t)pmb * 64 + tid] = L;
    }
    __syncthreads();
  }
}

// ============ legacy (R1-verified) f32-staging GEMM (prep + fallback) ======
__global__ __launch_bounds__(256) void gemm64_mfma(
    const float* __restrict__ A, int lda,
    const void* __restrict__ Wa, int ldwa,
    const void* __restrict__ Wb, int ldwb, int ksplit,
    const float* __restrict__ bias1, const float* __restrict__ bias2,
    float* __restrict__ C, size_t ldc,
    int K, int wbf16,
    float* __restrict__ pm, float* __restrict__ pl)
{
  __shared__ unsigned short As[2048];
  __shared__ unsigned short Bs[2048];
  __shared__ float Pm[4][64];
  __shared__ float Pl[4][64];

  const int tid  = threadIdx.x;
  const int lane = tid & 63;
  const int w    = tid >> 6;
  const int n0   = blockIdx.x * 64;

  f32x4 acc0 = {0.f,0.f,0.f,0.f}, acc1 = {0.f,0.f,0.f,0.f};
  f32x4 acc2 = {0.f,0.f,0.f,0.f}, acc3 = {0.f,0.f,0.f,0.f};

  for (int k0 = 0; k0 < K; k0 += 32) {
    #pragma unroll
    for (int ss = 0; ss < 2; ++ss) {
      int s  = tid + ss * 256;
      int r  = s >> 3;
      int kq = s & 7;
      int kL = kq * 4;
      int kg = k0 + kL;
      const float* ap = A + (size_t)r * lda + kg;
      float4 av = *(const float4*)ap;
      ushort4 au;
      au.x = f2bf(av.x); au.y = f2bf(av.y); au.z = f2bf(av.z); au.w = f2bf(av.w);
      int dst = ((r >> 4) << 9) + ((kL >> 3) << 7) + ((r & 15) << 3) + (kL & 7);
      *(ushort4*)&As[dst] = au;
      int n = n0 + r;
      ushort4 bu;
      if (wbf16) {
        const unsigned short* wpp = (kg < ksplit)
          ? (const unsigned short*)Wa + (size_t)n * ldwa + kg
          : (const unsigned short*)Wb + (size_t)n * ldwb + (kg - ksplit);
        bu = *(const ushort4*)wpp;
      } else {
        const float* wpp = (kg < ksplit)
          ? (const float*)Wa + (size_t)n * ldwa + kg
          : (const float*)Wb + (size_t)n * ldwb + (kg - ksplit);
        float4 wv = *(const float4*)wpp;
        bu.x = f2bf(wv.x); bu.y = f2bf(wv.y); bu.z = f2bf(wv.z); bu.w = f2bf(wv.w);
      }
      *(ushort4*)&Bs[dst] = bu;
    }
    __syncthreads();
    short8v bf = *(const short8v*)&Bs[(w << 9) + (lane << 3)];
    short8v a0 = *(const short8v*)&As[(0 << 9) + (lane << 3)];
    short8v a1 = *(const short8v*)&As[(1 << 9) + (lane << 3)];
    short8v a2 = *(const short8v*)&As[(2 << 9) + (lane << 3)];
    short8v a3 = *(const short8v*)&As[(3 << 9) + (lane << 3)];
    acc0 = __builtin_amdgcn_mfma_f32_16x16x32_bf16(a0, bf, acc0, 0, 0, 0);
    acc1 = __builtin_amdgcn_mfma_f32_16x16x32_bf16(a1, bf, acc1, 0, 0, 0);
    acc2 = __builtin_amdgcn_mfma_f32_16x16x32_bf16(a2, bf, acc2, 0, 0, 0);
    acc3 = __builtin_amdgcn_mfma_f32_16x16x32_bf16(a3, bf, acc3, 0, 0, 0);
    __syncthreads();
  }

  const int col = n0 + (w << 4) + (lane & 15);
  const float bv = (bias1 ? bias1[col] : 0.0f) + (bias2 ? bias2[col] : 0.0f);
  f32x4 accs[4] = {acc0, acc1, acc2, acc3};
  float vals[4][4];
  #pragma unroll
  for (int mb = 0; mb < 4; ++mb) {
    #pragma unroll
    for (int r = 0; r < 4; ++r) {
      int row = (mb << 4) + ((lane >> 4) << 2) + r;
      float v = accs[mb][r] + bv;
      vals[mb][r] = v;
      C[(size_t)row * ldc + col] = v;
    }
  }

  if (pm) {
    #pragma unroll
    for (int mb = 0; mb < 4; ++mb) {
      #pragma unroll
      for (int r = 0; r < 4; ++r) {
        float v = vals[mb][r];
        float m = v;
        #pragma unroll
        for (int d = 1; d < 16; d <<= 1) m = fmaxf(m, __shfl_xor(m, d));
        float e = __expf(v - m);
        #pragma unroll
        for (int d = 1; d < 16; d <<= 1) e += __shfl_xor(e, d);
        if ((lane & 15) == 0) {
          int row = (mb << 4) + ((lane >> 4) << 2) + r;
          Pm[w][row] = m;
          Pl[w][row] = e;
        }
      }
    }
    __syncthreads();
    if (tid < 64) {
      float M = Pm[0][tid];
      M = fmaxf(M, Pm[1][tid]); M = fmaxf(M, Pm[2][tid]); M = fmaxf(M, Pm[3][tid]);
      float L = Pl[0][tid] * __expf(Pm[0][tid] - M)
              + Pl[1][tid] * __expf(Pm[1][tid] - M)
              + Pl[2][tid] * __expf(Pm[2][tid] - M)
              + Pl[3][tid] * __expf(Pm[3][tid] - M);
      pm[(size_t)blockIdx.x * 64 + tid] = M;
      pl[(size_t)blockIdx.x * 64 + tid] = L;
    }
  }
}

// f32 -> bf16 bulk convert
__global__ __launch_bounds__(256) void k_f32_to_bf16(
    const float* __restrict__ src, unsigned short* __restrict__ dst, int n) {
  int i0 = (blockIdx.x * 256 + threadIdx.x) * 8;
  int stride = gridDim.x * 256 * 8;
  for (int i = i0; i < n; i += stride) {
    float4 a = *(const float4*)(src + i);
    float4 c = *(const float4*)(src + i + 4);
    ushort4 u1, u2;
    u1.x = f2bf(a.x); u1.y = f2bf(a.y); u1.z = f2bf(a.z); u1.w = f2bf(a.w);
    u2.x = f2bf(c.x); u2.y = f2bf(c.y); u2.z = f2bf(c.z); u2.w = f2bf(c.w);
    *(ushort4*)(dst + i)     = u1;
    *(ushort4*)(dst + i + 4) = u2;
  }
}

__global__ __launch_bounds__(256) void k_bias_sum(
    const float* __restrict__ a, const float* __restrict__ b,
    float* __restrict__ o, int n) {
  int i = blockIdx.x * 256 + threadIdx.x;
  if (i < n) o[i] = a[i] + b[i];
}

// normalize one 4096-elem unit of lp(t')
DEV void norm_apply(int j, float* __restrict__ lp_base, const float* __restrict__ logZ, int tid) {
  #pragma unroll
  for (int q = 0; q < 4; ++q) {
    size_t e = (size_t)j * 4096 + q * 1024 + tid * 4;
    int b = (int)(e / 32000);
    int r = (int)(e - (size_t)b * 32000);
    float4* p = (float4*)(lp_base + (size_t)b * T * V + r);
    float z = logZ[b];
    float4 v = *p;
    v.x -= z; v.y -= z; v.z -= z; v.w -= z;
    *p = v;
  }
}

// logZ reduce over 500 tiles for batch b (pm layout [tile][64])
DEV void logz_reduce(LogZSm& z, const float* __restrict__ pm,
                     const float* __restrict__ pl, int b, float* __restrict__ dst) {
  const int tid = threadIdx.x;
  float m1 = pm[(size_t)tid * 64 + b];
  float l1 = pl[(size_t)tid * 64 + b];
  int j2 = tid + 256;
  if (j2 < NBL) {
    float m2 = pm[(size_t)j2 * 64 + b], l2 = pl[(size_t)j2 * 64 + b];
    float M = fmaxf(m1, m2);
    l1 = l1 * __expf(m1 - M) + l2 * __expf(m2 - M);
    m1 = M;
  }
  z.rm[tid] = m1; z.rl[tid] = l1;
  __syncthreads();
  for (int off = 128; off > 0; off >>= 1) {
    if (tid < off) {
      float ma = z.rm[tid], mb2 = z.rm[tid + off];
      float M = fmaxf(ma, mb2);
      z.rl[tid] = z.rl[tid] * __expf(ma - M) + z.rl[tid + off] * __expf(mb2 - M);
      z.rm[tid] = M;
    }
    __syncthreads();
  }
  if (tid == 0) dst[b] = z.rm[0] + __logf(z.rl[0]);
}

// ==== L1: qW1 split-K x4 (64) + logits(t-1) tiles [tile_off..) + norm(t-2) ====
// logits use hbt = h_t (slot t) = h_new of step t-1  ->  lp(t-1).  [R8 bug fix]
__global__ __launch_bounds__(256) void k_qw1_logits(
    const unsigned short* __restrict__ hbt, const unsigned short* __restrict__ w1b,
    float* __restrict__ qW1p,
    const unsigned short* __restrict__ outWb, const float* __restrict__ outb,
    float* __restrict__ lp_prev, float* __restrict__ pmv, float* __restrict__ plv,
    int nlg, int tile_off,
    float* __restrict__ lp_norm, const float* __restrict__ logZn, int norm_off)
{
  __shared__ GemmSm sm;
  const int bx = blockIdx.x;
  if (bx < 64) {
    const int kc = bx >> 4, nb = bx & 15;
    gemm_body2<false>(sm, hbt + kc * 256, H, w1b + kc * 256, H, 256, nb * 64,
                      qW1p + (size_t)kc * BH, H, nullptr, nullptr, nullptr, 0);
  } else if (bx < 64 + nlg) {
    const int tile = tile_off + (bx - 64);
    gemm_body2<true>(sm, hbt, H, outWb, H, H, tile * 64,
                     lp_prev, (size_t)T * V, outb, pmv, plv, tile);
  } else {
    norm_apply(norm_off + (bx - 64 - nlg), lp_norm, logZn, threadIdx.x);
  }
}

// ==== L2: fused attn (256) + logits(t-1) tiles [250..) + norm(t-2) ========
__global__ __launch_bounds__(256) void k_attn_logits(
    const float* __restrict__ qW1p, const float* __restrict__ b1,
    const float* __restrict__ keys, const float* __restrict__ Vw,
    const float* __restrict__ Vb,
    const float* __restrict__ enc, const float* __restrict__ emb,
    const int* __restrict__ tok,
    const unsigned short* __restrict__ hbt, unsigned short* __restrict__ xbufb,
    float* __restrict__ attn_out, int t,
    const unsigned short* __restrict__ outWb, const float* __restrict__ outb,
    float* __restrict__ lp_prev, float* __restrict__ pmv, float* __restrict__ plv,
    int nlg,
    float* __restrict__ lp_norm, const float* __restrict__ logZn)
{
  __shared__ StepSm u;
  const int tid = threadIdx.x;
  const int bx = blockIdx.x;
  if (bx >= 256) {
    if (bx < 256 + nlg) {
      const int tile = 250 + (bx - 256);
      gemm_body2<true>(u.g, hbt, H, outWb, H, H, tile * 64,
                       lp_prev, (size_t)T * V, outb, pmv, plv, tile);
    } else {
      norm_apply(250 + (bx - 256 - nlg), lp_norm, logZn, tid);
    }
    return;
  }
  AttnSm& s = u.a;
  const int b = bx >> 2, hq = bx & 3;

  #pragma unroll
  for (int i = 0; i < 4; ++i) {
    int idx = tid + i * 256;
    float q = b1[idx];
    q += qW1p[(size_t)0 * BH + b * H + idx];
    q += qW1p[(size_t)1 * BH + b * H + idx];
    q += qW1p[(size_t)2 * BH + b * H + idx];
    q += qW1p[(size_t)3 * BH + b * H + idx];
    s.qw[idx] = q;
    s.vw[idx] = Vw[idx];
  }
  __syncthreads();

  const int w = tid >> 6, lane = tid & 63;
  #pragma unroll
  for (int si = 0; si < 32; ++si) {
    int sg = w * 32 + si;
    const float* kp = keys + (size_t)sg * H;
    float p = 0.0f;
    #pragma unroll
    for (int uu = 0; uu < 16; ++uu) {
      int h = lane + (uu << 6);
      p += s.vw[h] * fast_tanh(s.qw[h] + kp[h]);
    }
    #pragma unroll
    for (int d = 1; d < 64; d <<= 1) p += __shfl_xor(p, d);
    if (lane == 0) s.sc[sg] = p + Vb[0];
  }
  __syncthreads();
  if (tid < 64) {
    float a0 = s.sc[tid], a1 = s.sc[tid + 64];
    float m = fmaxf(a0, a1);
    #pragma unroll
    for (int d = 1; d < 64; d <<= 1) m = fmaxf(m, __shfl_xor(m, d));
    float e0 = __expf(a0 - m), e1 = __expf(a1 - m);
    float sum = e0 + e1;
    #pragma unroll
    for (int d = 1; d < 64; d <<= 1) sum += __shfl_xor(sum, d);
    float v0 = e0 / sum, v1 = e1 / sum;
    s.al[tid] = v0; s.al[tid + 64] = v1;
    if (hq == 0) {
      attn_out[((size_t)t * B + b) * S + tid]      = v0;
      attn_out[((size_t)t * B + b) * S + tid + 64] = v1;
    }
  }
  __syncthreads();

  const int h = hq * 256 + tid;
  float acc = 0.0f;
  const float* ep = enc + (size_t)b * S * H + h;
  #pragma unroll 4
  for (int sx = 0; sx < S; ++sx) acc += s.al[sx] * ep[(size_t)sx * H];

  int token = tok[b * T + t];
  xbufb[(size_t)b * KX + h]         = f2bf(emb[(size_t)token * H + h]);
  xbufb[(size_t)b * KX + H + h]     = f2bf(acc);
  xbufb[(size_t)b * KX + 2 * H + h] = hbt[b * H + h];
}

// ==== L3: fused gates+cell (64, strided-N) + logZ(t-1) (64) ===============
// block j < 64: gate columns n = g*1024 + 16j + (0..15) for all 4 gates g
// (wave g), K=3072 over xbufb; then cell via LDS exchange.
__global__ __launch_bounds__(256) void k_gates_cell_ride(
    const unsigned short* __restrict__ xbufb,
    const unsigned short* __restrict__ wihb,
    const unsigned short* __restrict__ whhb,
    const float* __restrict__ bsum,
    float* __restrict__ cbuf, unsigned short* __restrict__ hb_next,
    float* __restrict__ out_h, float* __restrict__ out_c, int last,
    const float* __restrict__ pmv, const float* __restrict__ plv,
    float* __restrict__ logZ)
{
  __shared__ GemmSm sm;
  const int bx = blockIdx.x;
  const int tid = threadIdx.x;

  if (bx >= 64) {                         // logZ(t-1) ride
    LogZSm* zz = reinterpret_cast<LogZSm*>(&sm);
    logz_reduce(*zz, pmv, plv, bx - 64, logZ);
    return;
  }

  // ---- gates GEMM, strided-N mapping ----
  const int j = bx;
  const int l = tid & 63;
  const int w = tid >> 6;

  f32x4 acc0 = {0,0,0,0}, acc1 = {0,0,0,0}, acc2 = {0,0,0,0}, acc3 = {0,0,0,0};
  const int rA = l & 15;
  const int kq = (l >> 4) << 3;

  auto stage = [&](int k0, int buf) {
    #pragma unroll
    for (int i = 0; i < 4; ++i) {
      const int c    = (w << 2) | i;
      const int side = c >> 3;
      const int ks   = (c >> 2) & 1;
      const int mb   = c & 3;
      const int kk   = k0 + ks * 32 + kq;
      const int row  = mb * 16 + rA;
      const unsigned short* src;
      if (side) {
        const int n = ((row >> 4) << 10) + (j << 4) + (row & 15);
        src = (kk < 2048) ? wihb + (size_t)n * 2048 + kk
                          : whhb + (size_t)n * 1024 + (kk - 2048);
      } else {
        src = xbufb + (size_t)row * KX + kk;
      }
      unsigned short* dst = (side ? sm.Bs[buf] : sm.As[buf]) + ks * 2048 + mb * 512;
      gload16(src, dst);
    }
  };

  const int nk = KX >> 6;   // 48
  stage(0, 0);
  stage(64, 1);
  for (int kt = 0; kt < nk; ++kt) {
    const int buf = kt % 3;
    if (kt + 2 < nk) {
      stage((kt + 2) << 6, (kt + 2) % 3);
      asm volatile("s_waitcnt vmcnt(8)" ::: "memory");
    } else if (kt + 1 < nk) {
      asm volatile("s_waitcnt vmcnt(4)" ::: "memory");
    } else {
      asm volatile("s_waitcnt vmcnt(0)" ::: "memory");
    }
    __builtin_amdgcn_s_barrier();
    asm volatile("" ::: "memory");
    const unsigned short* __restrict__ asb = sm.As[buf];
    const unsigned short* __restrict__ bsb = sm.Bs[buf];
    #pragma unroll
    for (int ks = 0; ks < 2; ++ks) {
      short8v bf = *(const short8v*)&bsb[ks * 2048 + (w << 9) + (l << 3)];
      acc0 = __builtin_amdgcn_mfma_f32_16x16x32_bf16(*(const short8v*)&asb[ks * 2048 + 0 * 512 + (l << 3)], bf, acc0, 0, 0, 0);
      acc1 = __builtin_amdgcn_mfma_f32_16x16x32_bf16(*(const short8v*)&asb[ks * 2048 + 1 * 512 + (l << 3)], bf, acc1, 0, 0, 0);
      acc2 = __builtin_amdgcn_mfma_f32_16x16x32_bf16(*(const short8v*)&asb[ks * 2048 + 2 * 512 + (l << 3)], bf, acc2, 0, 0, 0);
      acc3 = __builtin_amdgcn_mfma_f32_16x16x32_bf16(*(const short8v*)&asb[ks * 2048 + 3 * 512 + (l << 3)], bf, acc3, 0, 0, 0);
    }
    asm volatile("" ::: "memory");
    __builtin_amdgcn_s_barrier();
  }

  // ---- epilogue: wave w holds gate w; exchange via LDS, apply cell ----
  float (*gs)[64][17] = reinterpret_cast<float (*)[64][17]>(&sm);
  const int hcol = l & 15;
  const float bv = bsum[(w << 10) + (j << 4) + hcol];
  f32x4 accs[4] = {acc0, acc1, acc2, acc3};
  __syncthreads();   // all waves past MFMA loop before LDS reuse
  #pragma unroll
  for (int mb = 0; mb < 4; ++mb) {
    #pragma unroll
    for (int r = 0; r < 4; ++r) {
      int row = (mb << 4) + ((l >> 4) << 2) + r;   // batch index
      gs[w][row][hcol] = accs[mb][r] + bv;
    }
  }
  __syncthreads();

  const int b   = tid >> 2;
  const int h16 = (tid & 3) << 2;
  const int hg  = (j << 4) + h16;
  float4 cp = *(const float4*)(cbuf + (size_t)b * H + hg);
  float cin[4] = {cp.x, cp.y, cp.z, cp.w};
  float hh[4], cc[4];
  #pragma unroll
  for (int jj = 0; jj < 4; ++jj) {
    float gi = gs[0][b][h16 + jj];
    float gf = gs[1][b][h16 + jj];
    float gg = gs[2][b][h16 + jj];
    float go = gs[3][b][h16 + jj];
    float c = fast_sig(gf) * cin[jj] + fast_sig(gi) * fast_tanh(gg);
    hh[jj] = fast_sig(go) * fast_tanh(c);
    cc[jj] = c;
  }
  float4 co = {cc[0], cc[1], cc[2], cc[3]};
  *(float4*)(cbuf + (size_t)b * H + hg) = co;
  ushort4 uh;
  uh.x = f2bf(hh[0]); uh.y = f2bf(hh[1]); uh.z = f2bf(hh[2]); uh.w = f2bf(hh[3]);
  *(ushort4*)(hb_next + (size_t)b * H + hg) = uh;
  if (last) {
    float4 ho = {hh[0], hh[1], hh[2], hh[3]};
    *(float4*)(out_h + (size_t)b * H + hg) = ho;
    *(float4*)(out_c + (size_t)b * H + hg) = co;
  }
}

// ==== tail: logits(T-1) from slot T (500) + norm(T-2) (500) ====
__global__ __launch_bounds__(256) void k_logits_norm_tail(
    const unsigned short* __restrict__ hbT,
    const unsigned short* __restrict__ outWb, const float* __restrict__ outb,
    float* __restrict__ lp_last, float* __restrict__ pmv, float* __restrict__ plv,
    float* __restrict__ lp_norm, const float* __restrict__ logZn)
{
  __shared__ GemmSm sm;
  const int bx = blockIdx.x;
  if (bx < NBL) {
    gemm_body2<true>(sm, hbT, H, outWb, H, H, bx * 64,
                     lp_last, (size_t)T * V, outb, pmv, plv, bx);
  } else {
    norm_apply(bx - NBL, lp_norm, logZn, threadIdx.x);
  }
}

__global__ __launch_bounds__(256) void k_logz_solo(
    const float* __restrict__ pmv, const float* __restrict__ plv,
    float* __restrict__ logZ)
{
  __shared__ LogZSm z;
  logz_reduce(z, pmv, plv, blockIdx.x, logZ);
}

__global__ __launch_bounds__(256) void k_norm_solo(
    float* __restrict__ lp_base, const float* __restrict__ logZ)
{
  norm_apply(blockIdx.x, lp_base, logZ, threadIdx.x);
}

// ================= legacy fallback kernels (R1-proven) =====================
__global__ __launch_bounds__(256) void k_scores_leg(
    const float* __restrict__ qW1, const float* __restrict__ keys,
    const float* __restrict__ Vw, const float* __restrict__ Vb,
    float* __restrict__ scores)
{
  __shared__ float qw[H];
  __shared__ float vw[H];
  const int b  = blockIdx.x >> 2;
  const int sq = blockIdx.x & 3;
  const int tid = threadIdx.x;
  #pragma unroll
  for (int i = 0; i < 4; ++i) {
    qw[tid + i * 256] = qW1[b * H + tid + i * 256];
    vw[tid + i * 256] = Vw[tid + i * 256];
  }
  __syncthreads();
  const int w = tid >> 6, lane = tid & 63;
  #pragma unroll
  for (int si = 0; si < 8; ++si) {
    int sg = sq * 32 + w * 8 + si;
    const float* kp = keys + (size_t)sg * H;
    float p = 0.0f;
    #pragma unroll
    for (int u = 0; u < 16; ++u) {
      int h = lane + (u << 6);
      p += vw[h] * fast_tanh(qw[h] + kp[h]);
    }
    #pragma unroll
    for (int d = 1; d < 64; d <<= 1) p += __shfl_xor(p, d);
    if (lane == 0) scores[b * S + sg] = p + Vb[0];
  }
}

__global__ __launch_bounds__(256) void k_attn_ctx_leg(
    const float* __restrict__ scores, const float* __restrict__ enc,
    const float* __restrict__ emb, const int* __restrict__ tok,
    const float* __restrict__ hcur, float* __restrict__ xbuf,
    float* __restrict__ attn_out, int t)
{
  __shared__ float al[S];
  __shared__ float wred[4];
  const int b   = blockIdx.x >> 2;
  const int hq  = blockIdx.x & 3;
  const int tid = threadIdx.x;

  float sv = (tid < S) ? scores[b * S + tid] : -1e30f;
  float m = sv;
  #pragma unroll
  for (int d = 1; d < 64; d <<= 1) m = fmaxf(m, __shfl_xor(m, d));
  if ((tid & 63) == 0) wred[tid >> 6] = m;
  __syncthreads();
  m = fmaxf(fmaxf(wred[0], wred[1]), fmaxf(wred[2], wred[3]));
  float e = (tid < S) ? __expf(sv - m) : 0.0f;
  float ssum = e;
  #pragma unroll
  for (int d = 1; d < 64; d <<= 1) ssum += __shfl_xor(ssum, d);
  __syncthreads();
  if ((tid & 63) == 0) wred[tid >> 6] = ssum;
  __syncthreads();
  float tot = wred[0] + wred[1] + wred[2] + wred[3];
  float a = e / tot;
  if (tid < S) {
    al[tid] = a;
    if (hq == 0) attn_out[((size_t)t * B + b) * S + tid] = a;
  }
  __syncthreads();

  const int h = hq * 256 + tid;
  float acc = 0.0f;
  const float* ep = enc + (size_t)b * S * H + h;
  #pragma unroll 4
  for (int s = 0; s < S; ++s) acc += al[s] * ep[(size_t)s * H];

  int token = tok[b * T + t];
  xbuf[b * KX + h]         = emb[(size_t)token * H + h];
  xbuf[b * KX + H + h]     = acc;
  xbuf[b * KX + 2 * H + h] = hcur[b * H + h];
}

__global__ __launch_bounds__(256) void k_cell_leg(
    const float* __restrict__ gates, const float* __restrict__ cprev,
    float* __restrict__ hnew, float* __restrict__ cnew,
    float* __restrict__ hout, float* __restrict__ cout, int last)
{
  int idx = blockIdx.x * 256 + threadIdx.x;
  int b = idx >> 10, h = idx & 1023;
  const float* g = gates + (size_t)b * H4;
  float gi = g[h], gf = g[H + h], gg = g[2 * H + h], go = g[3 * H + h];
  float c = fast_sig(gf) * cprev[idx] + fast_sig(gi) * fast_tanh(gg);
  float hv = fast_sig(go) * fast_tanh(c);
  cnew[idx] = c;
  hnew[idx] = hv;
  if (last) { hout[idx] = hv; cout[idx] = c; }
}

__global__ __launch_bounds__(256) void k_norm_leg(
    const float* __restrict__ pm, const float* __restrict__ pl,
    float* __restrict__ lp, int t)
{
  __shared__ float rm[256], rl[256];
  const int bx = blockIdx.x;
  const int b  = bx / 125;
  const int ch = bx % 125;
  const int tid = threadIdx.x;

  float m1 = pm[(size_t)tid * 64 + b];
  float l1 = pl[(size_t)tid * 64 + b];
  int nb2 = tid + 256;
  if (nb2 < NBL) {
    float m2 = pm[(size_t)nb2 * 64 + b];
    float l2 = pl[(size_t)nb2 * 64 + b];
    float M = fmaxf(m1, m2);
    l1 = l1 * __expf(m1 - M) + l2 * __expf(m2 - M);
    m1 = M;
  }
  rm[tid] = m1; rl[tid] = l1;
  __syncthreads();
  for (int off = 128; off > 0; off >>= 1) {
    if (tid < off) {
      float ma = rm[tid], mb = rm[tid + off];
      float M = fmaxf(ma, mb);
      rl[tid] = rl[tid] * __expf(ma - M) + rl[tid + off] * __expf(mb - M);
      rm[tid] = M;
    }
    __syncthreads();
  }
  float logZ = rm[0] + __logf(rl[0]);
  size_t base = ((size_t)b * T + t) * V + (size_t)ch * 256;
  lp[base + tid] -= logZ;
}

// ============================ host launcher ================================
static void run_legacy(void* const* d_in, void* d_out, void* d_ws, size_t ws_size,
                       hipStream_t stream)
{
  const float* enc  = (const float*)d_in[0];
  const float* eh   = (const float*)d_in[1];
  const float* ec   = (const float*)d_in[2];
  const int*   tok  = (const int*)d_in[4];
  const float* emb  = (const float*)d_in[5];
  const float* W1   = (const float*)d_in[6];
  const float* b1   = (const float*)d_in[7];
  const float* W2   = (const float*)d_in[8];
  const float* b2   = (const float*)d_in[9];
  const float* Vw   = (const float*)d_in[10];
  const float* Vb   = (const float*)d_in[11];
  const float* W_ih = (const float*)d_in[12];
  const float* W_hh = (const float*)d_in[13];
  const float* b_ih = (const float*)d_in[14];
  const float* b_hh = (const float*)d_in[15];
  const float* outW = (const float*)d_in[16];
  const float* outb = (const float*)d_in[17];
  const float* br1W = (const float*)d_in[18];
  const float* br1b = (const float*)d_in[19];
  const float* br2W = (const float*)d_in[20];
  const float* br2b = (const float*)d_in[21];

  float* out    = (float*)d_out;
  float* out_h  = out + (size_t)B * T * V;
  float* out_c  = out_h + BH;
  float* out_at = out_c + BH;

  char* wp = (char*)d_ws;
  auto alloc = [&](size_t bytes) {
    char* p = wp; wp += (bytes + 255) & ~(size_t)255; return p;
  };
  float* keysL   = (float*)alloc((size_t)S * H * 4);
  float* hbuf0   = (float*)alloc((size_t)BH * 4);
  float* hbuf1   = (float*)alloc((size_t)BH * 4);
  float* cbuf0L  = (float*)alloc((size_t)BH * 4);
  float* cbuf1L  = (float*)alloc((size_t)BH * 4);
  float* qW1vL   = (float*)alloc((size_t)BH * 4);
  float* scoresL = (float*)alloc((size_t)B * S * 4);
  float* xbuf    = (float*)alloc((size_t)B * KX * 4);
  float* gates   = (float*)alloc((size_t)B * H4 * 4);
  float* pmvL    = (float*)alloc((size_t)NBL * 64 * 4);
  float* plvL    = (float*)alloc((size_t)NBL * 64 * 4);
  unsigned short* outWbL = (unsigned short*)alloc((size_t)V * H * 2);
  size_t need_out = (size_t)(wp - (char*)d_ws);
  unsigned short* wihbL = (unsigned short*)alloc((size_t)H4 * 2 * H * 2);
  unsigned short* whhbL = (unsigned short*)alloc((size_t)H4 * H * 2);
  unsigned short* w1bL  = (unsigned short*)alloc((size_t)H * H * 2);
  size_t need_all = (size_t)(wp - (char*)d_ws);

  const bool cvtOut = ws_size >= need_out;
  const bool cvtAll = ws_size >= need_all;

  if (cvtOut) k_f32_to_bf16<<<4096, 256, 0, stream>>>(outW, outWbL, V * H);
  if (cvtAll) {
    k_f32_to_bf16<<<2048, 256, 0, stream>>>(W_ih, wihbL, H4 * 2 * H);
    k_f32_to_bf16<<<1024, 256, 0, stream>>>(W_hh, whhbL, H4 * H);
    k_f32_to_bf16<<<256, 256, 0, stream>>>(W1, w1bL, H * H);
  }

  gemm64_mfma<<<16, 256, 0, stream>>>(enc,          H, W2, H, W2, H, H, b2, nullptr, keysL,          H, H, 0, nullptr, nullptr);
  gemm64_mfma<<<16, 256, 0, stream>>>(enc + 64 * H, H, W2, H, W2, H, H, b2, nullptr, keysL + 64 * H, H, H, 0, nullptr, nullptr);
  gemm64_mfma<<<16, 256, 0, stream>>>(eh, H, br1W, H, br1W, H, H, br1b, nullptr, hbuf0, H, H, 0, nullptr, nullptr);
  gemm64_mfma<<<16, 256, 0, stream>>>(ec, H, br2W, H, br2W, H, H, br2b, nullptr, cbuf0L, H, H, 0, nullptr, nullptr);

  float* hb[2] = {hbuf0, hbuf1};
  float* cb[2] = {cbuf0L, cbuf1L};

  for (int t = 0; t < T; ++t) {
    const int cur = t & 1, nxt = cur ^ 1;
    if (cvtAll)
      gemm64_mfma<<<16, 256, 0, stream>>>(hb[cur], H, w1bL, H, w1bL, H, H, b1, nullptr, qW1vL, H, H, 1, nullptr, nullptr);
    else
      gemm64_mfma<<<16, 256, 0, stream>>>(hb[cur], H, W1, H, W1, H, H, b1, nullptr, qW1vL, H, H, 0, nullptr, nullptr);
    k_scores_leg<<<256, 256, 0, stream>>>(qW1vL, keysL, Vw, Vb, scoresL);
    k_attn_ctx_leg<<<256, 256, 0, stream>>>(scoresL, enc, emb, tok, hb[cur], xbuf, out_at, t);
    if (cvtAll)
      gemm64_mfma<<<64, 256, 0, stream>>>(xbuf, KX, wihbL, 2 * H, whhbL, H, 2 * H, b_ih, b_hh, gates, H4, KX, 1, nullptr, nullptr);
    else
      gemm64_mfma<<<64, 256, 0, stream>>>(xbuf, KX, W_ih, 2 * H, W_hh, H, 2 * H, b_ih, b_hh, gates, H4, KX, 0, nullptr, nullptr);
    k_cell_leg<<<256, 256, 0, stream>>>(gates, cb[cur], hb[nxt], cb[nxt], out_h, out_c, t == T - 1);
    if (cvtOut)
      gemm64_mfma<<<NBL, 256, 0, stream>>>(hb[nxt], H, outWbL, H, outWbL, H, H, outb, nullptr, out + (size_t)t * V, (size_t)T * V, H, 1, pmvL, plvL);
    else
      gemm64_mfma<<<NBL, 256, 0, stream>>>(hb[nxt], H, outW, H, outW, H, H, outb, nullptr, out + (size_t)t * V, (size_t)T * V, H, 0, pmvL, plvL);
    k_norm_leg<<<64 * 125, 256, 0, stream>>>(pmvL, plvL, out, t);
  }
}

extern "C" void kernel_launch(void* const* d_in, const int* in_sizes, int n_in,
                              void* d_out, int out_size, void* d_ws, size_t ws_size,
                              hipStream_t stream)
{
  (void)in_sizes; (void)n_in; (void)out_size;
  const float* enc  = (const float*)d_in[0];
  const float* eh   = (const float*)d_in[1];
  const float* ec   = (const float*)d_in[2];
  const int*   tok  = (const int*)d_in[4];
  const float* emb  = (const float*)d_in[5];
  const float* W1   = (const float*)d_in[6];
  const float* b1   = (const float*)d_in[7];
  const float* W2   = (const float*)d_in[8];
  const float* b2   = (const float*)d_in[9];
  const float* Vw   = (const float*)d_in[10];
  const float* Vb   = (const float*)d_in[11];
  const float* W_ih = (const float*)d_in[12];
  const float* W_hh = (const float*)d_in[13];
  const float* b_ih = (const float*)d_in[14];
  const float* b_hh = (const float*)d_in[15];
  const float* outW = (const float*)d_in[16];
  const float* outb = (const float*)d_in[17];
  const float* br1W = (const float*)d_in[18];
  const float* br1b = (const float*)d_in[19];
  const float* br2W = (const float*)d_in[20];
  const float* br2b = (const float*)d_in[21];

  float* out    = (float*)d_out;
  float* out_lp = out;
  float* out_h  = out + (size_t)B * T * V;
  float* out_c  = out_h + BH;
  float* out_at = out_c + BH;

  char* wp = (char*)d_ws;
  auto alloc = [&](size_t bytes) {
    char* p = wp; wp += (bytes + 255) & ~(size_t)255; return p;
  };
  float* keys   = (float*)alloc((size_t)S * H * 4);
  float* cbuf   = (float*)alloc((size_t)BH * 4);
  float* h0f    = (float*)alloc((size_t)BH * 4);
  float* qW1p   = (float*)alloc((size_t)4 * BH * 4);
  float* bsum   = (float*)alloc((size_t)H4 * 4);
  unsigned short* xbufb = (unsigned short*)alloc((size_t)B * KX * 2);
  float* pmv    = (float*)alloc((size_t)NBL * 64 * 4);
  float* plv    = (float*)alloc((size_t)NBL * 64 * 4);
  float* logZ   = (float*)alloc((size_t)2 * B * 4);
  unsigned short* hhistb = (unsigned short*)alloc((size_t)(T + 1) * BH * 2);
  unsigned short* w1b  = (unsigned short*)alloc((size_t)H * H * 2);
  unsigned short* wihb = (unsigned short*)alloc((size_t)H4 * 2 * H * 2);
  unsigned short* whhb = (unsigned short*)alloc((size_t)H4 * H * 2);
  unsigned short* outWb = (unsigned short*)alloc((size_t)V * H * 2);
  size_t need_fast = (size_t)(wp - (char*)d_ws);

  if (ws_size < need_fast) {
    run_legacy(d_in, d_out, d_ws, ws_size, stream);
    return;
  }

  // ---- prep ----
  k_f32_to_bf16<<<2048, 256, 0, stream>>>(W_ih, wihb, H4 * 2 * H);
  k_f32_to_bf16<<<1024, 256, 0, stream>>>(W_hh, whhb, H4 * H);
  k_f32_to_bf16<<<256, 256, 0, stream>>>(W1, w1b, H * H);
  k_f32_to_bf16<<<4096, 256, 0, stream>>>(outW, outWb, V * H);
  k_bias_sum<<<16, 256, 0, stream>>>(b_ih, b_hh, bsum, H4);

  gemm64_mfma<<<16, 256, 0, stream>>>(enc,          H, W2, H, W2, H, H, b2, nullptr, keys,          H, H, 0, nullptr, nullptr);
  gemm64_mfma<<<16, 256, 0, stream>>>(enc + 64 * H, H, W2, H, W2, H, H, b2, nullptr, keys + 64 * H, H, H, 0, nullptr, nullptr);
  gemm64_mfma<<<16, 256, 0, stream>>>(eh, H, br1W, H, br1W, H, H, br1b, nullptr, h0f, H, H, 0, nullptr, nullptr);
  gemm64_mfma<<<16, 256, 0, stream>>>(ec, H, br2W, H, br2W, H, H, br2b, nullptr, cbuf, H, H, 0, nullptr, nullptr);
  k_f32_to_bf16<<<32, 256, 0, stream>>>(h0f, hhistb, BH);    // h_0 -> slot 0

  // ---- 32 steps x 3 launches; logits(t-1)/logZ(t-1)/norm(t-2) ride ----
  for (int t = 0; t < T; ++t) {
    const unsigned short* hbt = hhistb + (size_t)t * BH;
    const int nlg   = (t >= 1) ? 250 : 0;     // logits(t-1) tiles per kernel
    const int nnorm = (t >= 2) ? 250 : 0;     // norm(t-2) units per kernel
    float* lp_prev = (t >= 1) ? out_lp + (size_t)(t - 1) * V : out_lp;
    float* lp_norm = (t >= 2) ? out_lp + (size_t)(t - 2) * V : out_lp;
    const float* logZn = logZ + ((t - 2) & 1) * B;
    k_qw1_logits<<<64 + nlg + nnorm, 256, 0, stream>>>(
        hbt, w1b, qW1p, outWb, outb, lp_prev, pmv, plv, nlg, 0,
        lp_norm, logZn, 0);
    k_attn_logits<<<256 + nlg + nnorm, 256, 0, stream>>>(
        qW1p, b1, keys, Vw, Vb, enc, emb, tok, hbt, xbufb, out_at, t,
        outWb, outb, lp_prev, pmv, plv, nlg, lp_norm, logZn);
    const int nlz = (t >= 1) ? 64 : 0;
    k_gates_cell_ride<<<64 + nlz, 256, 0, stream>>>(
        xbufb, wihb, whhb, bsum, cbuf, hhistb + (size_t)(t + 1) * BH,
        out_h, out_c, t == T - 1,
        pmv, plv, logZ + ((t - 1) & 1) * B);
  }

  // ---- tail: logits(T-1) from slot T + norm(T-2); logZ(T-1); norm(T-1) ----
  k_logits_norm_tail<<<NBL + NBL, 256, 0, stream>>>(
      hhistb + (size_t)T * BH, outWb, outb,
      out_lp + (size_t)(T - 1) * V, pmv, plv,
      out_lp + (size_t)(T - 2) * V, logZ + ((T - 2) & 1) * B);
  k_logz_solo<<<64, 256, 0, stream>>>(pmv, plv, logZ + ((T - 1) & 1) * B);
  k_norm_solo<<<NBL, 256, 0, stream>>>(out_lp + (size_t)(T - 1) * V,
                                       logZ + ((T - 1) & 1) * B);
}

// Round 10
// 2958.150 us; speedup vs baseline: 1.7183x; 1.2380x over previous
//
#include <hip/hip_runtime.h>
#include <hip/hip_bf16.h>

#define DEV __device__ __forceinline__

constexpr int B = 64, S = 128, T = 32, H = 1024, V = 32000;
constexpr int H4 = 4096;          // 4*H
constexpr int KX = 3072;          // [emb | ctx | h]
constexpr int NBL = V / 64;       // 500 logits N-tiles
constexpr int BH = B * H;

using f32x4   = __attribute__((ext_vector_type(4))) float;
using short8v = __attribute__((ext_vector_type(8))) short;

DEV unsigned short f2bf(float x) {
  union { __hip_bfloat16 b; unsigned short u; } v;
  v.b = __float2bfloat16(x);
  return v.u;
}
DEV float fast_sig(float x) { return 1.0f / (1.0f + __expf(-x)); }
DEV float fast_tanh(float x) {
  float e = __expf(2.0f * x);
  return 1.0f - 2.0f / (e + 1.0f);
}

DEV void gload16(const void* g, void* l) {
  __builtin_amdgcn_global_load_lds(
      (const __attribute__((address_space(1))) void*)g,
      (__attribute__((address_space(3))) void*)l, 16, 0, 0);
}

// ---------------- LDS ----------------
struct GemmSm {
  unsigned short As[3][4096];
  unsigned short Bs[3][4096];
  float Pm[4][64];
  float Pl[4][64];
};
struct AttnSm { float qw[H]; float vw[H]; float sc[S]; float al[S]; };
struct LogZSm { float rm[256]; float rl[256]; };
union StepSm { GemmSm g; AttnSm a; LogZSm z; };

// ============ pipelined bf16 GEMM body (M=64, Ntile=64, BK=64) ============
// verified fragment layout: lane l's 16B at l*16 -> row=mb*16+(l&15),
// k=ks*32+(l>>4)*8..+7 ; 3 LDS buffers, 2-deep prefetch, counted vmcnt.
template<bool PARTIALS>
DEV void gemm_body2(GemmSm& sm,
                    const unsigned short* __restrict__ A, int lda,
                    const unsigned short* __restrict__ W, int ldw,
                    int K, int n0,
                    float* __restrict__ C, size_t ldc,
                    const float* __restrict__ bias,
                    float* __restrict__ pm, float* __restrict__ pl, int pmb)
{
  const int tid = threadIdx.x;
  const int l   = tid & 63;
  const int w   = tid >> 6;

  f32x4 acc0 = {0,0,0,0}, acc1 = {0,0,0,0}, acc2 = {0,0,0,0}, acc3 = {0,0,0,0};

  const int rA = l & 15;
  const int kq = (l >> 4) << 3;

  auto stage = [&](int k0, int buf) {
    #pragma unroll
    for (int i = 0; i < 4; ++i) {
      const int c    = (w << 2) | i;
      const int side = c >> 3;
      const int ks   = (c >> 2) & 1;
      const int mb   = c & 3;
      const int kk   = k0 + ks * 32 + kq;
      const int row  = mb * 16 + rA;
      const unsigned short* src = side
        ? W + (size_t)(n0 + row) * ldw + kk
        : A + (size_t)row * lda + kk;
      unsigned short* dst = (side ? sm.Bs[buf] : sm.As[buf]) + ks * 2048 + mb * 512;
      gload16(src, dst);
    }
  };

  const int nk = K >> 6;
  stage(0, 0);
  if (nk > 1) stage(64, 1);
  for (int kt = 0; kt < nk; ++kt) {
    const int buf = kt % 3;
    if (kt + 2 < nk) {
      stage((kt + 2) << 6, (kt + 2) % 3);
      asm volatile("s_waitcnt vmcnt(8)" ::: "memory");
    } else if (kt + 1 < nk) {
      asm volatile("s_waitcnt vmcnt(4)" ::: "memory");
    } else {
      asm volatile("s_waitcnt vmcnt(0)" ::: "memory");
    }
    __builtin_amdgcn_s_barrier();
    asm volatile("" ::: "memory");
    const unsigned short* __restrict__ asb = sm.As[buf];
    const unsigned short* __restrict__ bsb = sm.Bs[buf];
    #pragma unroll
    for (int ks = 0; ks < 2; ++ks) {
      short8v bf = *(const short8v*)&bsb[ks * 2048 + (w << 9) + (l << 3)];
      acc0 = __builtin_amdgcn_mfma_f32_16x16x32_bf16(*(const short8v*)&asb[ks * 2048 + 0 * 512 + (l << 3)], bf, acc0, 0, 0, 0);
      acc1 = __builtin_amdgcn_mfma_f32_16x16x32_bf16(*(const short8v*)&asb[ks * 2048 + 1 * 512 + (l << 3)], bf, acc1, 0, 0, 0);
      acc2 = __builtin_amdgcn_mfma_f32_16x16x32_bf16(*(const short8v*)&asb[ks * 2048 + 2 * 512 + (l << 3)], bf, acc2, 0, 0, 0);
      acc3 = __builtin_amdgcn_mfma_f32_16x16x32_bf16(*(const short8v*)&asb[ks * 2048 + 3 * 512 + (l << 3)], bf, acc3, 0, 0, 0);
    }
    asm volatile("" ::: "memory");
    __builtin_amdgcn_s_barrier();
  }

  const int col = n0 + (w << 4) + (l & 15);
  const float bv = bias ? bias[col] : 0.0f;
  f32x4 accs[4] = {acc0, acc1, acc2, acc3};
  float vals[4][4];
  #pragma unroll
  for (int mb = 0; mb < 4; ++mb) {
    #pragma unroll
    for (int r = 0; r < 4; ++r) {
      int row = (mb << 4) + ((l >> 4) << 2) + r;
      float v = accs[mb][r] + bv;
      vals[mb][r] = v;
      C[(size_t)row * ldc + col] = v;
    }
  }

  if (PARTIALS) {
    #pragma unroll
    for (int mb = 0; mb < 4; ++mb) {
      #pragma unroll
      for (int r = 0; r < 4; ++r) {
        float v = vals[mb][r];
        float m = v;
        #pragma unroll
        for (int d = 1; d < 16; d <<= 1) m = fmaxf(m, __shfl_xor(m, d));
        float e = __expf(v - m);
        #pragma unroll
        for (int d = 1; d < 16; d <<= 1) e += __shfl_xor(e, d);
        if ((l & 15) == 0) {
          int row = (mb << 4) + ((l >> 4) << 2) + r;
          sm.Pm[w][row] = m;
          sm.Pl[w][row] = e;
        }
      }
    }
    __syncthreads();
    if (tid < 64) {
      float M = sm.Pm[0][tid];
      M = fmaxf(M, sm.Pm[1][tid]); M = fmaxf(M, sm.Pm[2][tid]); M = fmaxf(M, sm.Pm[3][tid]);
      float L = sm.Pl[0][tid] * __expf(sm.Pm[0][tid] - M)
              + sm.Pl[1][tid] * __expf(sm.Pm[1][tid] - M)
              + sm.Pl[2][tid] * __expf(sm.Pm[2][tid] - M)
              + sm.Pl[3][tid] * __expf(sm.Pm[3][tid] - M);
      pm[(size_t)pmb * 64 + tid] = M;
      pl[(size_t)pmb * 64 + tid] = L;
    }
    __syncthreads();
  }
}

// ============ legacy (R1-verified) f32-staging GEMM body, parameterized ====
DEV void legacy_body(unsigned short* As, unsigned short* Bs,
                     float (*Pm)[64], float (*Pl)[64],
                     const float* __restrict__ A, int lda,
                     const void* __restrict__ Wa, int ldwa,
                     const void* __restrict__ Wb, int ldwb, int ksplit,
                     const float* __restrict__ bias1, const float* __restrict__ bias2,
                     float* __restrict__ C, size_t ldc,
                     int K, int wbf16,
                     float* __restrict__ pm, float* __restrict__ pl,
                     int n0, int pmb)
{
  const int tid  = threadIdx.x;
  const int lane = tid & 63;
  const int w    = tid >> 6;

  f32x4 acc0 = {0.f,0.f,0.f,0.f}, acc1 = {0.f,0.f,0.f,0.f};
  f32x4 acc2 = {0.f,0.f,0.f,0.f}, acc3 = {0.f,0.f,0.f,0.f};

  for (int k0 = 0; k0 < K; k0 += 32) {
    #pragma unroll
    for (int ss = 0; ss < 2; ++ss) {
      int s  = tid + ss * 256;
      int r  = s >> 3;
      int kq = s & 7;
      int kL = kq * 4;
      int kg = k0 + kL;
      const float* ap = A + (size_t)r * lda + kg;
      float4 av = *(const float4*)ap;
      ushort4 au;
      au.x = f2bf(av.x); au.y = f2bf(av.y); au.z = f2bf(av.z); au.w = f2bf(av.w);
      int dst = ((r >> 4) << 9) + ((kL >> 3) << 7) + ((r & 15) << 3) + (kL & 7);
      *(ushort4*)&As[dst] = au;
      int n = n0 + r;
      ushort4 bu;
      if (wbf16) {
        const unsigned short* wpp = (kg < ksplit)
          ? (const unsigned short*)Wa + (size_t)n * ldwa + kg
          : (const unsigned short*)Wb + (size_t)n * ldwb + (kg - ksplit);
        bu = *(const ushort4*)wpp;
      } else {
        const float* wpp = (kg < ksplit)
          ? (const float*)Wa + (size_t)n * ldwa + kg
          : (const float*)Wb + (size_t)n * ldwb + (kg - ksplit);
        float4 wv = *(const float4*)wpp;
        bu.x = f2bf(wv.x); bu.y = f2bf(wv.y); bu.z = f2bf(wv.z); bu.w = f2bf(wv.w);
      }
      *(ushort4*)&Bs[dst] = bu;
    }
    __syncthreads();
    short8v bf = *(const short8v*)&Bs[(w << 9) + (lane << 3)];
    short8v a0 = *(const short8v*)&As[(0 << 9) + (lane << 3)];
    short8v a1 = *(const short8v*)&As[(1 << 9) + (lane << 3)];
    short8v a2 = *(const short8v*)&As[(2 << 9) + (lane << 3)];
    short8v a3 = *(const short8v*)&As[(3 << 9) + (lane << 3)];
    acc0 = __builtin_amdgcn_mfma_f32_16x16x32_bf16(a0, bf, acc0, 0, 0, 0);
    acc1 = __builtin_amdgcn_mfma_f32_16x16x32_bf16(a1, bf, acc1, 0, 0, 0);
    acc2 = __builtin_amdgcn_mfma_f32_16x16x32_bf16(a2, bf, acc2, 0, 0, 0);
    acc3 = __builtin_amdgcn_mfma_f32_16x16x32_bf16(a3, bf, acc3, 0, 0, 0);
    __syncthreads();
  }

  const int col = n0 + (w << 4) + (lane & 15);
  const float bv = (bias1 ? bias1[col] : 0.0f) + (bias2 ? bias2[col] : 0.0f);
  f32x4 accs[4] = {acc0, acc1, acc2, acc3};
  float vals[4][4];
  #pragma unroll
  for (int mb = 0; mb < 4; ++mb) {
    #pragma unroll
    for (int r = 0; r < 4; ++r) {
      int row = (mb << 4) + ((lane >> 4) << 2) + r;
      float v = accs[mb][r] + bv;
      vals[mb][r] = v;
      C[(size_t)row * ldc + col] = v;
    }
  }

  if (pm) {
    #pragma unroll
    for (int mb = 0; mb < 4; ++mb) {
      #pragma unroll
      for (int r = 0; r < 4; ++r) {
        float v = vals[mb][r];
        float m = v;
        #pragma unroll
        for (int d = 1; d < 16; d <<= 1) m = fmaxf(m, __shfl_xor(m, d));
        float e = __expf(v - m);
        #pragma unroll
        for (int d = 1; d < 16; d <<= 1) e += __shfl_xor(e, d);
        if ((lane & 15) == 0) {
          int row = (mb << 4) + ((lane >> 4) << 2) + r;
          Pm[w][row] = m;
          Pl[w][row] = e;
        }
      }
    }
    __syncthreads();
    if (tid < 64) {
      float M = Pm[0][tid];
      M = fmaxf(M, Pm[1][tid]); M = fmaxf(M, Pm[2][tid]); M = fmaxf(M, Pm[3][tid]);
      float L = Pl[0][tid] * __expf(Pm[0][tid] - M)
              + Pl[1][tid] * __expf(Pm[1][tid] - M)
              + Pl[2][tid] * __expf(Pm[2][tid] - M)
              + Pl[3][tid] * __expf(Pm[3][tid] - M);
      pm[(size_t)pmb * 64 + tid] = M;
      pl[(size_t)pmb * 64 + tid] = L;
    }
  }
}

__global__ __launch_bounds__(256) void gemm64_mfma(
    const float* __restrict__ A, int lda,
    const void* __restrict__ Wa, int ldwa,
    const void* __restrict__ Wb, int ldwb, int ksplit,
    const float* __restrict__ bias1, const float* __restrict__ bias2,
    float* __restrict__ C, size_t ldc,
    int K, int wbf16,
    float* __restrict__ pm, float* __restrict__ pl)
{
  __shared__ unsigned short As[2048];
  __shared__ unsigned short Bs[2048];
  __shared__ float Pm[4][64];
  __shared__ float Pl[4][64];
  legacy_body(As, Bs, Pm, Pl, A, lda, Wa, ldwa, Wb, ldwb, ksplit,
              bias1, bias2, C, ldc, K, wbf16, pm, pl,
              blockIdx.x * 64, blockIdx.x);
}

// f32 -> bf16 bulk convert (single region)
__global__ __launch_bounds__(256) void k_f32_to_bf16(
    const float* __restrict__ src, unsigned short* __restrict__ dst, int n) {
  int i0 = (blockIdx.x * 256 + threadIdx.x) * 8;
  int stride = gridDim.x * 256 * 8;
  for (int i = i0; i < n; i += stride) {
    float4 a = *(const float4*)(src + i);
    float4 c = *(const float4*)(src + i + 4);
    ushort4 u1, u2;
    u1.x = f2bf(a.x); u1.y = f2bf(a.y); u1.z = f2bf(a.z); u1.w = f2bf(a.w);
    u2.x = f2bf(c.x); u2.y = f2bf(c.y); u2.z = f2bf(c.z); u2.w = f2bf(c.w);
    *(ushort4*)(dst + i)     = u1;
    *(ushort4*)(dst + i + 4) = u2;
  }
}

// all 4 weight conversions in one launch (region-routed, grid 2880)
__global__ __launch_bounds__(256) void k_cvt_all(
    const float* __restrict__ outW, unsigned short* __restrict__ outWb,
    const float* __restrict__ W_ih, unsigned short* __restrict__ wihb,
    const float* __restrict__ W_hh, unsigned short* __restrict__ whhb,
    const float* __restrict__ W1, unsigned short* __restrict__ w1b)
{
  const int bx = blockIdx.x;
  const float* src; unsigned short* dst; int n, b0, nb;
  if (bx < 2048)      { src = outW; dst = outWb; n = V * H;      b0 = 0;    nb = 2048; }
  else if (bx < 2560) { src = W_ih; dst = wihb;  n = H4 * 2 * H; b0 = 2048; nb = 512; }
  else if (bx < 2816) { src = W_hh; dst = whhb;  n = H4 * H;     b0 = 2560; nb = 256; }
  else                { src = W1;   dst = w1b;   n = H * H;      b0 = 2816; nb = 64; }
  int i0 = ((bx - b0) * 256 + threadIdx.x) * 8;
  int stride = nb * 256 * 8;
  for (int i = i0; i < n; i += stride) {
    float4 a = *(const float4*)(src + i);
    float4 c = *(const float4*)(src + i + 4);
    ushort4 u1, u2;
    u1.x = f2bf(a.x); u1.y = f2bf(a.y); u1.z = f2bf(a.z); u1.w = f2bf(a.w);
    u2.x = f2bf(c.x); u2.y = f2bf(c.y); u2.z = f2bf(c.z); u2.w = f2bf(c.w);
    *(ushort4*)(dst + i)     = u1;
    *(ushort4*)(dst + i + 4) = u2;
  }
}

// 4 prep GEMMs in one launch (64 blocks)
__global__ __launch_bounds__(256) void k_prep4(
    const float* __restrict__ enc, const float* __restrict__ W2,
    const float* __restrict__ b2,
    const float* __restrict__ eh, const float* __restrict__ br1W,
    const float* __restrict__ br1b,
    const float* __restrict__ ec, const float* __restrict__ br2W,
    const float* __restrict__ br2b,
    float* __restrict__ keys, float* __restrict__ h0f, float* __restrict__ cbuf0)
{
  __shared__ unsigned short As[2048];
  __shared__ unsigned short Bs[2048];
  __shared__ float Pm[4][64];
  __shared__ float Pl[4][64];
  const int bx = blockIdx.x;
  if (bx < 16)
    legacy_body(As, Bs, Pm, Pl, enc, H, W2, H, W2, H, H, b2, nullptr,
                keys, H, H, 0, nullptr, nullptr, bx * 64, 0);
  else if (bx < 32)
    legacy_body(As, Bs, Pm, Pl, enc + 64 * H, H, W2, H, W2, H, H, b2, nullptr,
                keys + 64 * H, H, H, 0, nullptr, nullptr, (bx - 16) * 64, 0);
  else if (bx < 48)
    legacy_body(As, Bs, Pm, Pl, eh, H, br1W, H, br1W, H, H, br1b, nullptr,
                h0f, H, H, 0, nullptr, nullptr, (bx - 32) * 64, 0);
  else
    legacy_body(As, Bs, Pm, Pl, ec, H, br2W, H, br2W, H, H, br2b, nullptr,
                cbuf0, H, H, 0, nullptr, nullptr, (bx - 48) * 64, 0);
}

// normalize one 4096-elem unit of lp(t')
DEV void norm_apply(int j, float* __restrict__ lp_base, const float* __restrict__ logZ, int tid) {
  #pragma unroll
  for (int q = 0; q < 4; ++q) {
    size_t e = (size_t)j * 4096 + q * 1024 + tid * 4;
    int b = (int)(e / 32000);
    int r = (int)(e - (size_t)b * 32000);
    float4* p = (float4*)(lp_base + (size_t)b * T * V + r);
    float z = logZ[b];
    float4 v = *p;
    v.x -= z; v.y -= z; v.z -= z; v.w -= z;
    *p = v;
  }
}

// logZ reduce over 500 tiles for batch b (pm layout [tile][64])
DEV void logz_reduce(LogZSm& z, const float* __restrict__ pm,
                     const float* __restrict__ pl, int b, float* __restrict__ dst) {
  const int tid = threadIdx.x;
  float m1 = pm[(size_t)tid * 64 + b];
  float l1 = pl[(size_t)tid * 64 + b];
  int j2 = tid + 256;
  if (j2 < NBL) {
    float m2 = pm[(size_t)j2 * 64 + b], l2 = pl[(size_t)j2 * 64 + b];
    float M = fmaxf(m1, m2);
    l1 = l1 * __expf(m1 - M) + l2 * __expf(m2 - M);
    m1 = M;
  }
  z.rm[tid] = m1; z.rl[tid] = l1;
  __syncthreads();
  for (int off = 128; off > 0; off >>= 1) {
    if (tid < off) {
      float ma = z.rm[tid], mb2 = z.rm[tid + off];
      float M = fmaxf(ma, mb2);
      z.rl[tid] = z.rl[tid] * __expf(ma - M) + z.rl[tid + off] * __expf(mb2 - M);
      z.rm[tid] = M;
    }
    __syncthreads();
  }
  if (tid == 0) dst[b] = z.rm[0] + __logf(z.rl[0]);
}

// ==== A: qW1 split-K x4 (64) + logits(t-1) tiles + norm(t-2) units ========
__global__ __launch_bounds__(256) void k_qw1_logits(
    const unsigned short* __restrict__ hbt, const unsigned short* __restrict__ w1b,
    float* __restrict__ qW1p,
    const unsigned short* __restrict__ outWb, const float* __restrict__ outb,
    float* __restrict__ lp_prev, float* __restrict__ pmv, float* __restrict__ plv,
    int nlg, int tile_off,
    float* __restrict__ lp_norm, const float* __restrict__ logZn, int norm_off)
{
  __shared__ GemmSm sm;
  const int bx = blockIdx.x;
  if (bx < 64) {
    const int kc = bx >> 4, nb = bx & 15;
    gemm_body2<false>(sm, hbt + kc * 256, H, w1b + kc * 256, H, 256, nb * 64,
                      qW1p + (size_t)kc * BH, H, nullptr, nullptr, nullptr, 0);
  } else if (bx < 64 + nlg) {
    const int tile = tile_off + (bx - 64);
    gemm_body2<true>(sm, hbt, H, outWb, H, H, tile * 64,
                     lp_prev, (size_t)T * V, outb, pmv, plv, tile);
  } else {
    norm_apply(norm_off + (bx - 64 - nlg), lp_norm, logZn, threadIdx.x);
  }
}

// ==== B: merged scores+softmax+ctx+xbuf (64, non-redundant) + rides =======
__global__ __launch_bounds__(256) void k_attn_merged(
    const float* __restrict__ qW1p, const float* __restrict__ b1,
    const float* __restrict__ keys, const float* __restrict__ Vw,
    const float* __restrict__ Vb,
    const float* __restrict__ enc, const float* __restrict__ emb,
    const int* __restrict__ tok,
    const unsigned short* __restrict__ hbt, unsigned short* __restrict__ xbufb,
    float* __restrict__ attn_out, int t,
    const unsigned short* __restrict__ outWb, const float* __restrict__ outb,
    float* __restrict__ lp_prev, float* __restrict__ pmv, float* __restrict__ plv,
    int nlg, int tile_off,
    float* __restrict__ lp_norm, const float* __restrict__ logZn, int norm_off)
{
  __shared__ StepSm u;
  const int tid = threadIdx.x;
  const int bx = blockIdx.x;
  if (bx >= 64) {
    if (bx < 64 + nlg) {
      const int tile = tile_off + (bx - 64);
      gemm_body2<true>(u.g, hbt, H, outWb, H, H, tile * 64,
                       lp_prev, (size_t)T * V, outb, pmv, plv, tile);
    } else {
      norm_apply(norm_off + (bx - 64 - nlg), lp_norm, logZn, tid);
    }
    return;
  }
  AttnSm& s = u.a;
  const int b = bx;

  #pragma unroll
  for (int i = 0; i < 4; ++i) {
    int idx = tid + i * 256;
    float q = b1[idx];
    q += qW1p[(size_t)0 * BH + b * H + idx];
    q += qW1p[(size_t)1 * BH + b * H + idx];
    q += qW1p[(size_t)2 * BH + b * H + idx];
    q += qW1p[(size_t)3 * BH + b * H + idx];
    s.qw[idx] = q;
    s.vw[idx] = Vw[idx];
  }
  __syncthreads();

  const int w = tid >> 6, lane = tid & 63;
  // non-redundant: wave w computes s-values w*32..w*32+31 (4x32 = 128)
  for (int si = 0; si < 32; ++si) {
    int sg = w * 32 + si;
    const float* kp = keys + (size_t)sg * H;
    float p = 0.0f;
    #pragma unroll
    for (int uu = 0; uu < 16; ++uu) {
      int h = lane + (uu << 6);
      p += s.vw[h] * fast_tanh(s.qw[h] + kp[h]);
    }
    #pragma unroll
    for (int d = 1; d < 64; d <<= 1) p += __shfl_xor(p, d);
    if (lane == 0) s.sc[sg] = p + Vb[0];
  }
  __syncthreads();
  if (tid < 64) {
    float a0 = s.sc[tid], a1 = s.sc[tid + 64];
    float m = fmaxf(a0, a1);
    #pragma unroll
    for (int d = 1; d < 64; d <<= 1) m = fmaxf(m, __shfl_xor(m, d));
    float e0 = __expf(a0 - m), e1 = __expf(a1 - m);
    float sum = e0 + e1;
    #pragma unroll
    for (int d = 1; d < 64; d <<= 1) sum += __shfl_xor(sum, d);
    float v0 = e0 / sum, v1 = e1 / sum;
    s.al[tid] = v0; s.al[tid + 64] = v1;
    attn_out[((size_t)t * B + b) * S + tid]      = v0;
    attn_out[((size_t)t * B + b) * S + tid + 64] = v1;
  }
  __syncthreads();

  // ctx: thread tid covers h = tid*4..+3 (full H per block)
  const int h0i = tid * 4;
  float4 acc = {0, 0, 0, 0};
  const float* ep = enc + (size_t)b * S * H + h0i;
  for (int sx = 0; sx < S; ++sx) {
    float4 e4 = *(const float4*)(ep + (size_t)sx * H);
    float av = s.al[sx];
    acc.x += av * e4.x; acc.y += av * e4.y; acc.z += av * e4.z; acc.w += av * e4.w;
  }
  int token = tok[b * T + t];
  float4 em = *(const float4*)(emb + (size_t)token * H + h0i);
  ushort4 ue, uc;
  ue.x = f2bf(em.x);  ue.y = f2bf(em.y);  ue.z = f2bf(em.z);  ue.w = f2bf(em.w);
  uc.x = f2bf(acc.x); uc.y = f2bf(acc.y); uc.z = f2bf(acc.z); uc.w = f2bf(acc.w);
  unsigned short* xb = xbufb + (size_t)b * KX;
  *(ushort4*)(xb + h0i)         = ue;
  *(ushort4*)(xb + H + h0i)     = uc;
  *(ushort4*)(xb + 2 * H + h0i) = *(const ushort4*)(hbt + (size_t)b * H + h0i);
}

// ==== C: gates split-K x6 (384) + logits(t-1) tiles [334..) ===============
__global__ __launch_bounds__(256) void k_gates_logits(
    const unsigned short* __restrict__ xbufb,
    const unsigned short* __restrict__ wihb,
    const unsigned short* __restrict__ whhb,
    float* __restrict__ gpart,
    const unsigned short* __restrict__ hbt,
    const unsigned short* __restrict__ outWb, const float* __restrict__ outb,
    float* __restrict__ lp_prev, float* __restrict__ pmv, float* __restrict__ plv)
{
  __shared__ GemmSm sm;
  const int bx = blockIdx.x;
  if (bx < 384) {
    const int kc = bx >> 6, nb = bx & 63;
    const unsigned short* A;
    const unsigned short* W;
    int ldw;
    if (kc < 4) { A = xbufb + kc * 512; W = wihb + kc * 512; ldw = 2 * H; }
    else        { A = xbufb + 2048 + (kc - 4) * 512; W = whhb + (kc - 4) * 512; ldw = H; }
    gemm_body2<false>(sm, A, KX, W, ldw, 512, nb * 64,
                      gpart + (size_t)kc * B * H4, (size_t)H4, nullptr, nullptr, nullptr, 0);
  } else {
    const int tile = 334 + (bx - 384);
    gemm_body2<true>(sm, hbt, H, outWb, H, H, tile * 64,
                     lp_prev, (size_t)T * V, outb, pmv, plv, tile);
  }
}

// ==== D: cell (256, 6 partials) + logZ(t-1) (64) ==========================
__global__ __launch_bounds__(256) void k_cell_logz(
    const float* __restrict__ gpart, const float* __restrict__ b_ih,
    const float* __restrict__ b_hh, const float* __restrict__ cprev,
    float* __restrict__ cnew, unsigned short* __restrict__ hb_next,
    float* __restrict__ out_h, float* __restrict__ out_c, int last,
    const float* __restrict__ pmv, const float* __restrict__ plv,
    float* __restrict__ logZ)
{
  __shared__ LogZSm z;
  const int bx = blockIdx.x;
  const int tid = threadIdx.x;
  if (bx < 256) {
    const int idx = bx * 256 + tid;
    const int b = idx >> 10, h = idx & 1023;
    float gi = b_ih[h]         + b_hh[h];
    float gf = b_ih[H + h]     + b_hh[H + h];
    float gg = b_ih[2 * H + h] + b_hh[2 * H + h];
    float go = b_ih[3 * H + h] + b_hh[3 * H + h];
    #pragma unroll
    for (int p = 0; p < 6; ++p) {
      const float* g = gpart + (size_t)p * B * H4 + (size_t)b * H4;
      gi += g[h]; gf += g[H + h]; gg += g[2 * H + h]; go += g[3 * H + h];
    }
    float c = fast_sig(gf) * cprev[idx] + fast_sig(gi) * fast_tanh(gg);
    float hv = fast_sig(go) * fast_tanh(c);
    cnew[idx] = c;
    hb_next[idx] = f2bf(hv);
    if (last) { out_h[idx] = hv; out_c[idx] = c; }
  } else {
    logz_reduce(z, pmv, plv, bx - 256, logZ);
  }
}

// ==== tail ====
__global__ __launch_bounds__(256) void k_logits_norm_tail(
    const unsigned short* __restrict__ hbT,
    const unsigned short* __restrict__ outWb, const float* __restrict__ outb,
    float* __restrict__ lp_last, float* __restrict__ pmv, float* __restrict__ plv,
    float* __restrict__ lp_norm, const float* __restrict__ logZn)
{
  __shared__ GemmSm sm;
  const int bx = blockIdx.x;
  if (bx < NBL) {
    gemm_body2<true>(sm, hbT, H, outWb, H, H, bx * 64,
                     lp_last, (size_t)T * V, outb, pmv, plv, bx);
  } else {
    norm_apply(bx - NBL, lp_norm, logZn, threadIdx.x);
  }
}

__global__ __launch_bounds__(256) void k_logz_solo(
    const float* __restrict__ pmv, const float* __restrict__ plv,
    float* __restrict__ logZ)
{
  __shared__ LogZSm z;
  logz_reduce(z, pmv, plv, blockIdx.x, logZ);
}

__global__ __launch_bounds__(256) void k_norm_solo(
    float* __restrict__ lp_base, const float* __restrict__ logZ)
{
  norm_apply(blockIdx.x, lp_base, logZ, threadIdx.x);
}

// ================= legacy fallback kernels (R1-proven) =====================
__global__ __launch_bounds__(256) void k_scores_leg(
    const float* __restrict__ qW1, const float* __restrict__ keys,
    const float* __restrict__ Vw, const float* __restrict__ Vb,
    float* __restrict__ scores)
{
  __shared__ float qw[H];
  __shared__ float vw[H];
  const int b  = blockIdx.x >> 2;
  const int sq = blockIdx.x & 3;
  const int tid = threadIdx.x;
  #pragma unroll
  for (int i = 0; i < 4; ++i) {
    qw[tid + i * 256] = qW1[b * H + tid + i * 256];
    vw[tid + i * 256] = Vw[tid + i * 256];
  }
  __syncthreads();
  const int w = tid >> 6, lane = tid & 63;
  #pragma unroll
  for (int si = 0; si < 8; ++si) {
    int sg = sq * 32 + w * 8 + si;
    const float* kp = keys + (size_t)sg * H;
    float p = 0.0f;
    #pragma unroll
    for (int u = 0; u < 16; ++u) {
      int h = lane + (u << 6);
      p += vw[h] * fast_tanh(qw[h] + kp[h]);
    }
    #pragma unroll
    for (int d = 1; d < 64; d <<= 1) p += __shfl_xor(p, d);
    if (lane == 0) scores[b * S + sg] = p + Vb[0];
  }
}

__global__ __launch_bounds__(256) void k_attn_ctx_leg(
    const float* __restrict__ scores, const float* __restrict__ enc,
    const float* __restrict__ emb, const int* __restrict__ tok,
    const float* __restrict__ hcur, float* __restrict__ xbuf,
    float* __restrict__ attn_out, int t)
{
  __shared__ float al[S];
  __shared__ float wred[4];
  const int b   = blockIdx.x >> 2;
  const int hq  = blockIdx.x & 3;
  const int tid = threadIdx.x;

  float sv = (tid < S) ? scores[b * S + tid] : -1e30f;
  float m = sv;
  #pragma unroll
  for (int d = 1; d < 64; d <<= 1) m = fmaxf(m, __shfl_xor(m, d));
  if ((tid & 63) == 0) wred[tid >> 6] = m;
  __syncthreads();
  m = fmaxf(fmaxf(wred[0], wred[1]), fmaxf(wred[2], wred[3]));
  float e = (tid < S) ? __expf(sv - m) : 0.0f;
  float ssum = e;
  #pragma unroll
  for (int d = 1; d < 64; d <<= 1) ssum += __shfl_xor(ssum, d);
  __syncthreads();
  if ((tid & 63) == 0) wred[tid >> 6] = ssum;
  __syncthreads();
  float tot = wred[0] + wred[1] + wred[2] + wred[3];
  float a = e / tot;
  if (tid < S) {
    al[tid] = a;
    if (hq == 0) attn_out[((size_t)t * B + b) * S + tid] = a;
  }
  __syncthreads();

  const int h = hq * 256 + tid;
  float acc = 0.0f;
  const float* ep = enc + (size_t)b * S * H + h;
  #pragma unroll 4
  for (int s = 0; s < S; ++s) acc += al[s] * ep[(size_t)s * H];

  int token = tok[b * T + t];
  xbuf[b * KX + h]         = emb[(size_t)token * H + h];
  xbuf[b * KX + H + h]     = acc;
  xbuf[b * KX + 2 * H + h] = hcur[b * H + h];
}

__global__ __launch_bounds__(256) void k_cell_leg(
    const float* __restrict__ gates, const float* __restrict__ cprev,
    float* __restrict__ hnew, float* __restrict__ cnew,
    float* __restrict__ hout, float* __restrict__ cout, int last)
{
  int idx = blockIdx.x * 256 + threadIdx.x;
  int b = idx >> 10, h = idx & 1023;
  const float* g = gates + (size_t)b * H4;
  float gi = g[h], gf = g[H + h], gg = g[2 * H + h], go = g[3 * H + h];
  float c = fast_sig(gf) * cprev[idx] + fast_sig(gi) * fast_tanh(gg);
  float hv = fast_sig(go) * fast_tanh(c);
  cnew[idx] = c;
  hnew[idx] = hv;
  if (last) { hout[idx] = hv; cout[idx] = c; }
}

__global__ __launch_bounds__(256) void k_norm_leg(
    const float* __restrict__ pm, const float* __restrict__ pl,
    float* __restrict__ lp, int t)
{
  __shared__ float rm[256], rl[256];
  const int bx = blockIdx.x;
  const int b  = bx / 125;
  const int ch = bx % 125;
  const int tid = threadIdx.x;

  float m1 = pm[(size_t)tid * 64 + b];
  float l1 = pl[(size_t)tid * 64 + b];
  int nb2 = tid + 256;
  if (nb2 < NBL) {
    float m2 = pm[(size_t)nb2 * 64 + b];
    float l2 = pl[(size_t)nb2 * 64 + b];
    float M = fmaxf(m1, m2);
    l1 = l1 * __expf(m1 - M) + l2 * __expf(m2 - M);
    m1 = M;
  }
  rm[tid] = m1; rl[tid] = l1;
  __syncthreads();
  for (int off = 128; off > 0; off >>= 1) {
    if (tid < off) {
      float ma = rm[tid], mb = rm[tid + off];
      float M = fmaxf(ma, mb);
      rl[tid] = rl[tid] * __expf(ma - M) + rl[tid + off] * __expf(mb - M);
      rm[tid] = M;
    }
    __syncthreads();
  }
  float logZ = rm[0] + __logf(rl[0]);
  size_t base = ((size_t)b * T + t) * V + (size_t)ch * 256;
  lp[base + tid] -= logZ;
}

// ============================ host launcher ================================
static void run_legacy(void* const* d_in, void* d_out, void* d_ws, size_t ws_size,
                       hipStream_t stream)
{
  const float* enc  = (const float*)d_in[0];
  const float* eh   = (const float*)d_in[1];
  const float* ec   = (const float*)d_in[2];
  const int*   tok  = (const int*)d_in[4];
  const float* emb  = (const float*)d_in[5];
  const float* W1   = (const float*)d_in[6];
  const float* b1   = (const float*)d_in[7];
  const float* W2   = (const float*)d_in[8];
  const float* b2   = (const float*)d_in[9];
  const float* Vw   = (const float*)d_in[10];
  const float* Vb   = (const float*)d_in[11];
  const float* W_ih = (const float*)d_in[12];
  const float* W_hh = (const float*)d_in[13];
  const float* b_ih = (const float*)d_in[14];
  const float* b_hh = (const float*)d_in[15];
  const float* outW = (const float*)d_in[16];
  const float* outb = (const float*)d_in[17];
  const float* br1W = (const float*)d_in[18];
  const float* br1b = (const float*)d_in[19];
  const float* br2W = (const float*)d_in[20];
  const float* br2b = (const float*)d_in[21];

  float* out    = (float*)d_out;
  float* out_h  = out + (size_t)B * T * V;
  float* out_c  = out_h + BH;
  float* out_at = out_c + BH;

  char* wp = (char*)d_ws;
  auto alloc = [&](size_t bytes) {
    char* p = wp; wp += (bytes + 255) & ~(size_t)255; return p;
  };
  float* keysL   = (float*)alloc((size_t)S * H * 4);
  float* hbuf0   = (float*)alloc((size_t)BH * 4);
  float* hbuf1   = (float*)alloc((size_t)BH * 4);
  float* cbuf0L  = (float*)alloc((size_t)BH * 4);
  float* cbuf1L  = (float*)alloc((size_t)BH * 4);
  float* qW1vL   = (float*)alloc((size_t)BH * 4);
  float* scoresL = (float*)alloc((size_t)B * S * 4);
  float* xbuf    = (float*)alloc((size_t)B * KX * 4);
  float* gates   = (float*)alloc((size_t)B * H4 * 4);
  float* pmvL    = (float*)alloc((size_t)NBL * 64 * 4);
  float* plvL    = (float*)alloc((size_t)NBL * 64 * 4);
  unsigned short* outWbL = (unsigned short*)alloc((size_t)V * H * 2);
  size_t need_out = (size_t)(wp - (char*)d_ws);
  unsigned short* wihbL = (unsigned short*)alloc((size_t)H4 * 2 * H * 2);
  unsigned short* whhbL = (unsigned short*)alloc((size_t)H4 * H * 2);
  unsigned short* w1bL  = (unsigned short*)alloc((size_t)H * H * 2);
  size_t need_all = (size_t)(wp - (char*)d_ws);

  const bool cvtOut = ws_size >= need_out;
  const bool cvtAll = ws_size >= need_all;

  if (cvtOut) k_f32_to_bf16<<<4096, 256, 0, stream>>>(outW, outWbL, V * H);
  if (cvtAll) {
    k_f32_to_bf16<<<2048, 256, 0, stream>>>(W_ih, wihbL, H4 * 2 * H);
    k_f32_to_bf16<<<1024, 256, 0, stream>>>(W_hh, whhbL, H4 * H);
    k_f32_to_bf16<<<256, 256, 0, stream>>>(W1, w1bL, H * H);
  }

  gemm64_mfma<<<16, 256, 0, stream>>>(enc,          H, W2, H, W2, H, H, b2, nullptr, keysL,          H, H, 0, nullptr, nullptr);
  gemm64_mfma<<<16, 256, 0, stream>>>(enc + 64 * H, H, W2, H, W2, H, H, b2, nullptr, keysL + 64 * H, H, H, 0, nullptr, nullptr);
  gemm64_mfma<<<16, 256, 0, stream>>>(eh, H, br1W, H, br1W, H, H, br1b, nullptr, hbuf0, H, H, 0, nullptr, nullptr);
  gemm64_mfma<<<16, 256, 0, stream>>>(ec, H, br2W, H, br2W, H, H, br2b, nullptr, cbuf0L, H, H, 0, nullptr, nullptr);

  float* hb[2] = {hbuf0, hbuf1};
  float* cb[2] = {cbuf0L, cbuf1L};

  for (int t = 0; t < T; ++t) {
    const int cur = t & 1, nxt = cur ^ 1;
    if (cvtAll)
      gemm64_mfma<<<16, 256, 0, stream>>>(hb[cur], H, w1bL, H, w1bL, H, H, b1, nullptr, qW1vL, H, H, 1, nullptr, nullptr);
    else
      gemm64_mfma<<<16, 256, 0, stream>>>(hb[cur], H, W1, H, W1, H, H, b1, nullptr, qW1vL, H, H, 0, nullptr, nullptr);
    k_scores_leg<<<256, 256, 0, stream>>>(qW1vL, keysL, Vw, Vb, scoresL);
    k_attn_ctx_leg<<<256, 256, 0, stream>>>(scoresL, enc, emb, tok, hb[cur], xbuf, out_at, t);
    if (cvtAll)
      gemm64_mfma<<<64, 256, 0, stream>>>(xbuf, KX, wihbL, 2 * H, whhbL, H, 2 * H, b_ih, b_hh, gates, H4, KX, 1, nullptr, nullptr);
    else
      gemm64_mfma<<<64, 256, 0, stream>>>(xbuf, KX, W_ih, 2 * H, W_hh, H, 2 * H, b_ih, b_hh, gates, H4, KX, 0, nullptr, nullptr);
    k_cell_leg<<<256, 256, 0, stream>>>(gates, cb[cur], hb[nxt], cb[nxt], out_h, out_c, t == T - 1);
    if (cvtOut)
      gemm64_mfma<<<NBL, 256, 0, stream>>>(hb[nxt], H, outWbL, H, outWbL, H, H, outb, nullptr, out + (size_t)t * V, (size_t)T * V, H, 1, pmvL, plvL);
    else
      gemm64_mfma<<<NBL, 256, 0, stream>>>(hb[nxt], H, outW, H, outW, H, H, outb, nullptr, out + (size_t)t * V, (size_t)T * V, H, 0, pmvL, plvL);
    k_norm_leg<<<64 * 125, 256, 0, stream>>>(pmvL, plvL, out, t);
  }
}

extern "C" void kernel_launch(void* const* d_in, const int* in_sizes, int n_in,
                              void* d_out, int out_size, void* d_ws, size_t ws_size,
                              hipStream_t stream)
{
  (void)in_sizes; (void)n_in; (void)out_size;
  const float* enc  = (const float*)d_in[0];
  const float* eh   = (const float*)d_in[1];
  const float* ec   = (const float*)d_in[2];
  const int*   tok  = (const int*)d_in[4];
  const float* emb  = (const float*)d_in[5];
  const float* W1   = (const float*)d_in[6];
  const float* b1   = (const float*)d_in[7];
  const float* W2   = (const float*)d_in[8];
  const float* b2   = (const float*)d_in[9];
  const float* Vw   = (const float*)d_in[10];
  const float* Vb   = (const float*)d_in[11];
  const float* W_ih = (const float*)d_in[12];
  const float* W_hh = (const float*)d_in[13];
  const float* b_ih = (const float*)d_in[14];
  const float* b_hh = (const float*)d_in[15];
  const float* outW = (const float*)d_in[16];
  const float* outb = (const float*)d_in[17];
  const float* br1W = (const float*)d_in[18];
  const float* br1b = (const float*)d_in[19];
  const float* br2W = (const float*)d_in[20];
  const float* br2b = (const float*)d_in[21];

  float* out    = (float*)d_out;
  float* out_lp = out;
  float* out_h  = out + (size_t)B * T * V;
  float* out_c  = out_h + BH;
  float* out_at = out_c + BH;

  char* wp = (char*)d_ws;
  auto alloc = [&](size_t bytes) {
    char* p = wp; wp += (bytes + 255) & ~(size_t)255; return p;
  };
  float* keys   = (float*)alloc((size_t)S * H * 4);
  float* cbuf0  = (float*)alloc((size_t)BH * 4);
  float* cbuf1  = (float*)alloc((size_t)BH * 4);
  float* h0f    = (float*)alloc((size_t)BH * 4);
  float* qW1p   = (float*)alloc((size_t)4 * BH * 4);
  unsigned short* xbufb = (unsigned short*)alloc((size_t)B * KX * 2);
  float* gpart  = (float*)alloc((size_t)6 * B * H4 * 4);
  float* pmv    = (float*)alloc((size_t)NBL * 64 * 4);
  float* plv    = (float*)alloc((size_t)NBL * 64 * 4);
  float* logZ   = (float*)alloc((size_t)2 * B * 4);
  unsigned short* hhistb = (unsigned short*)alloc((size_t)(T + 1) * BH * 2);
  unsigned short* w1b  = (unsigned short*)alloc((size_t)H * H * 2);
  unsigned short* wihb = (unsigned short*)alloc((size_t)H4 * 2 * H * 2);
  unsigned short* whhb = (unsigned short*)alloc((size_t)H4 * H * 2);
  unsigned short* outWb = (unsigned short*)alloc((size_t)V * H * 2);
  size_t need_fast = (size_t)(wp - (char*)d_ws);

  if (ws_size < need_fast) {
    run_legacy(d_in, d_out, d_ws, ws_size, stream);
    return;
  }

  // ---- prep: 3 launches ----
  k_cvt_all<<<2880, 256, 0, stream>>>(outW, outWb, W_ih, wihb, W_hh, whhb, W1, w1b);
  k_prep4<<<64, 256, 0, stream>>>(enc, W2, b2, eh, br1W, br1b, ec, br2W, br2b,
                                  keys, h0f, cbuf0);
  k_f32_to_bf16<<<32, 256, 0, stream>>>(h0f, hhistb, BH);    // h_0 -> slot 0

  float* cb[2] = {cbuf0, cbuf1};

  // ---- 32 steps x 4 launches; logits(t-1) 167/167/166 rides A/B/C,
  //      norm(t-2) 250/250 rides A/B, logZ(t-1) rides D ----
  for (int t = 0; t < T; ++t) {
    const unsigned short* hbt = hhistb + (size_t)t * BH;
    const int nlg  = (t >= 1) ? 167 : 0;
    const int nlg3 = (t >= 1) ? 166 : 0;
    const int nn   = (t >= 2) ? 250 : 0;
    float* lp_prev = (t >= 1) ? out_lp + (size_t)(t - 1) * V : out_lp;
    float* lp_norm = (t >= 2) ? out_lp + (size_t)(t - 2) * V : out_lp;
    const float* logZn = logZ + ((t - 2) & 1) * B;

    k_qw1_logits<<<64 + nlg + nn, 256, 0, stream>>>(
        hbt, w1b, qW1p, outWb, outb, lp_prev, pmv, plv, nlg, 0,
        lp_norm, logZn, 0);
    k_attn_merged<<<64 + nlg + nn, 256, 0, stream>>>(
        qW1p, b1, keys, Vw, Vb, enc, emb, tok, hbt, xbufb, out_at, t,
        outWb, outb, lp_prev, pmv, plv, nlg, 167, lp_norm, logZn, 250);
    k_gates_logits<<<384 + nlg3, 256, 0, stream>>>(
        xbufb, wihb, whhb, gpart, hbt, outWb, outb, lp_prev, pmv, plv);
    k_cell_logz<<<256 + (t >= 1 ? 64 : 0), 256, 0, stream>>>(
        gpart, b_ih, b_hh, cb[t & 1], cb[(t & 1) ^ 1],
        hhistb + (size_t)(t + 1) * BH, out_h, out_c, t == T - 1,
        pmv, plv, logZ + ((t - 1) & 1) * B);
  }

  // ---- tail: logits(T-1) from slot T + norm(T-2); logZ(T-1); norm(T-1) ----
  k_logits_norm_tail<<<NBL + NBL, 256, 0, stream>>>(
      hhistb + (size_t)T * BH, outWb, outb,
      out_lp + (size_t)(T - 1) * V, pmv, plv,
      out_lp + (size_t)(T - 2) * V, logZ + ((T - 2) & 1) * B);
  k_logz_solo<<<64, 256, 0, stream>>>(pmv, plv, logZ + ((T - 1) & 1) * B);
  k_norm_solo<<<NBL, 256, 0, stream>>>(out_lp + (size_t)(T - 1) * V,
                                       logZ + ((T - 1) & 1) * B);
}